// Round 4
// baseline (2303.255 us; speedup 1.0000x reference)
//
#include <hip/hip_runtime.h>
#include <math.h>

// ---------------- compile-time problem constants ----------------
#define TOTE 5400000   // total edges
#define TOTN 234000    // total node rows (all types concatenated)
#define TOTC 514000    // total dst slots over 14 edge types
#define HID  128

// bucketed CSR build (two-pass stable binning, no global atomics)
#define NBUK 499        // coarse dst-range buckets over all 14 edge types (span <= 2048 slots)
#define NBLK 1024       // blocks in hist_k / scatter_k (NBLK == 256*4 for scan_blk_k)

// ws carve (~224.4 MB, proven-safe ceiling 245.8 MB)
// d_out scratch: col (21.6MB), overwritten by the head GEMM at the end.

typedef __attribute__((ext_vector_type(8))) short short8;
typedef __attribute__((ext_vector_type(8))) __bf16 bf16x8;
typedef __attribute__((ext_vector_type(4))) float floatx4;

__constant__ int c_EPRE[15]   = {0,1000000,2000000,2500000,3000000,3200000,3400000,3600000,3800000,3900000,4000000,4300000,4600000,5000000,5400000};
__constant__ int c_ECNT[14]   = {1000000,1000000,500000,500000,200000,200000,200000,200000,100000,100000,300000,300000,400000,400000};
__constant__ int c_CNTOFF[14] = {0,40000,140000,143000,183000,203000,243000,263000,303000,311000,351000,411000,451000,454000};
__constant__ int c_CNTN[14]   = {40000,100000,3000,40000,20000,40000,20000,40000,8000,40000,60000,40000,3000,60000};
__constant__ int c_SRCOFF[14] = {0,100000,100000,140000,100000,143000,100000,143000,100000,163000,100000,171000,171000,231000};
__constant__ int c_NODEPRE[8] = {0,100000,140000,143000,163000,171000,231000,234000};
__constant__ float c_INVND[7] = {1.0f, 1.0f/6.0f, 1.0f, 0.5f, 1.0f, 0.5f, 1.0f};
// slot ranges feeding each dst node type (for update_k)
__constant__ int c_UPD_NS[7]      = {1,6,1,2,1,2,1};
__constant__ int c_UPD_BASE[7][6] = {
    {40000,0,0,0,0,0},
    {0,143000,203000,263000,311000,411000},
    {140000,0,0,0,0,0},
    {183000,243000,0,0,0,0},
    {303000,0,0,0,0,0},
    {351000,454000,0,0,0,0},
    {451000,0,0,0,0,0}};
// bucket tables: per-type dst shift and bucket-id base (prefix of ceil(CNTN/2^sh))
__constant__ int c_BSH[14]   = {9,10,6,10,10,11,10,11,10,11,11,11,6,11};
__constant__ int c_BBASE[15] = {0,79,177,224,264,284,304,324,344,352,372,402,422,469,499};

static __device__ __forceinline__ unsigned short f2bf(float f) {
    unsigned u = __float_as_uint(f);
    u = u + 0x7FFFu + ((u >> 16) & 1u);
    return (unsigned short)(u >> 16);
}
static __device__ __forceinline__ float bf2f(unsigned short s) {
    return __uint_as_float(((unsigned)s) << 16);
}
static __device__ __forceinline__ unsigned short f2h(float f) {
    _Float16 h = (_Float16)f;
    return __builtin_bit_cast(unsigned short, h);
}
static __device__ __forceinline__ float h2f(unsigned short s) {
    _Float16 h = __builtin_bit_cast(_Float16, s);
    return (float)h;
}

struct EdgeArgs { const int* ei[14]; };

// ---------------- CSR build: stable two-pass binning ----------------
// Record: (slot_local:11 | src_global:18), < 2^29.

__global__ __launch_bounds__(256) void hist_k(EdgeArgs a, int* __restrict__ blkHist) {
    __shared__ int h[NBUK];
    int t = threadIdx.x;
    for (int i = t; i < NBUK; i += 256) h[i] = 0;
    __syncthreads();
    const int per = (TOTE + NBLK - 1) / NBLK;
    int s = blockIdx.x * per;
    int eEnd = min(s + per, TOTE);
    for (int g = s + t; g < eEnd; g += 256) {
        int e = 0;
        while (g >= c_EPRE[e + 1]) e++;
        int k = g - c_EPRE[e];
        int dst = a.ei[e][c_ECNT[e] + k];
        atomicAdd(&h[c_BBASE[e] + (dst >> c_BSH[e])], 1);
    }
    __syncthreads();
    for (int i = t; i < NBUK; i += 256) blkHist[(size_t)i * NBLK + blockIdx.x] = h[i];
}

__global__ __launch_bounds__(256) void scan_blk_k(int* __restrict__ blkHist, int* __restrict__ bktCnt) {
    int b = blockIdx.x;
    int* p = blkHist + (size_t)b * NBLK;
    int t = threadIdx.x;
    int4 v = *(int4*)&p[t * 4];
    int s = v.x + v.y + v.z + v.w;
    int lane = t & 63, w = t >> 6;
    __shared__ int wt[4];
    int incl = s;
    #pragma unroll
    for (int d = 1; d < 64; d <<= 1) { int o = __shfl_up(incl, d); if (lane >= d) incl += o; }
    if (lane == 63) wt[w] = incl;
    __syncthreads();
    int wb = 0;
    for (int i = 0; i < w; i++) wb += wt[i];
    int excl = incl - s + wb;
    int4 o;
    o.x = excl; o.y = excl + v.x; o.z = excl + v.x + v.y; o.w = excl + v.x + v.y + v.z;
    *(int4*)&p[t * 4] = o;
    if (t == 255) bktCnt[b] = excl + s;
}

__global__ __launch_bounds__(512) void scans2_k(const int* __restrict__ bktCnt, int* __restrict__ bktEdgeBase) {
    int t = threadIdx.x;
    int v = (t < NBUK) ? bktCnt[t] : 0;
    int lane = t & 63, w = t >> 6;
    __shared__ int wt[8];
    int incl = v;
    #pragma unroll
    for (int d = 1; d < 64; d <<= 1) { int o = __shfl_up(incl, d); if (lane >= d) incl += o; }
    if (lane == 63) wt[w] = incl;
    __syncthreads();
    int wb = 0;
    for (int i = 0; i < w; i++) wb += wt[i];
    int excl = incl - v + wb;
    if (t < NBUK) bktEdgeBase[t] = excl;
    if (t == NBUK - 1) bktEdgeBase[NBUK] = excl + v;
}

__global__ __launch_bounds__(256) void scatter_k(EdgeArgs a, const int* __restrict__ blkHist,
        const int* __restrict__ bktEdgeBase, unsigned* __restrict__ pool) {
    __shared__ int cur[NBUK];
    int t = threadIdx.x;
    for (int i = t; i < NBUK; i += 256)
        cur[i] = bktEdgeBase[i] + blkHist[(size_t)i * NBLK + blockIdx.x];
    __syncthreads();
    const int per = (TOTE + NBLK - 1) / NBLK;
    int s = blockIdx.x * per;
    int eEnd = min(s + per, TOTE);
    for (int g = s + t; g < eEnd; g += 256) {
        int e = 0;
        while (g >= c_EPRE[e + 1]) e++;
        int k = g - c_EPRE[e];
        int src = a.ei[e][k];
        int dst = a.ei[e][c_ECNT[e] + k];
        int sh = c_BSH[e];
        unsigned rec = ((unsigned)(dst & ((1 << sh) - 1)) << 18) | (unsigned)(c_SRCOFF[e] + src);
        int p = atomicAdd(&cur[c_BBASE[e] + (dst >> sh)], 1);
        pool[p] = rec;
    }
}

__global__ __launch_bounds__(256) void csrfill_k(
        const unsigned* __restrict__ pool, const int* __restrict__ bktEdgeBase,
        int* __restrict__ cnt, int* __restrict__ cursor, float* __restrict__ invdeg,
        int* __restrict__ col) {
    __shared__ int hist[2048];
    __shared__ int cur[2048];
    __shared__ int wtot[4];
    __shared__ int wbase[4];
    int b = blockIdx.x;
    int t = threadIdx.x;
    int e = 0;
    while (b >= c_BBASE[e + 1]) e++;
    int lb = b - c_BBASE[e];
    int sh = c_BSH[e];
    int s0t = lb << sh;
    int span = min(1 << sh, c_CNTN[e] - s0t);
    int gs0 = c_CNTOFF[e] + s0t;
    int ebase = bktEdgeBase[b];
    int nrec = bktEdgeBase[b + 1] - ebase;

    for (int i = t; i < span; i += 256) hist[i] = 0;
    __syncthreads();
    for (int i = t; i < nrec; i += 256) atomicAdd(&hist[pool[ebase + i] >> 18], 1);
    __syncthreads();
    int base = t * 8, loc = 0, lv[8];
    #pragma unroll
    for (int i = 0; i < 8; i++) {
        int ii = base + i;
        int v = (ii < span) ? hist[ii] : 0;
        lv[i] = loc; loc += v;
    }
    int lane = t & 63, w = t >> 6;
    int incl = loc;
    #pragma unroll
    for (int d = 1; d < 64; d <<= 1) { int o = __shfl_up(incl, d); if (lane >= d) incl += o; }
    if (lane == 63) wtot[w] = incl;
    __syncthreads();
    if (t == 0) { int s2 = 0; for (int i = 0; i < 4; i++) { wbase[i] = s2; s2 += wtot[i]; } }
    __syncthreads();
    int texcl = incl - loc + wbase[w];
    #pragma unroll
    for (int i = 0; i < 8; i++) {
        int ii = base + i;
        if (ii < span) cur[ii] = texcl + lv[i];
    }
    __syncthreads();
    for (int i = t; i < span; i += 256) {
        int c = hist[i];
        cnt[gs0 + i] = c;
        cursor[gs0 + i] = ebase + cur[i] + c;     // end semantics
        invdeg[gs0 + i] = 1.0f / fmaxf((float)c, 1.0f);
    }
    __syncthreads();
    for (int i = t; i < nrec; i += 256) {
        unsigned rec = pool[ebase + i];
        int p = atomicAdd(&cur[rec >> 18], 1);
        col[ebase + p] = (int)(rec & 0x3FFFFu);
    }
}

// ---------------- conversions ----------------
struct XArgs { const float* x[7]; };
__global__ __launch_bounds__(256) void convx_k(XArgs a, unsigned short* __restrict__ hbf) {
    int i4 = blockIdx.x * 256 + threadIdx.x;
    if (i4 >= TOTN * 32) return;           // float4 index
    int idx = i4 * 4;
    int t = 0;
    while (idx >= c_NODEPRE[t + 1] * 128) t++;
    float4 v = *(const float4*)&a.x[t][idx - c_NODEPRE[t] * 128];
    uint2 p;
    p.x = (unsigned)f2bf(v.x) | ((unsigned)f2bf(v.y) << 16);
    p.y = (unsigned)f2bf(v.z) | ((unsigned)f2bf(v.w) << 16);
    *(uint2*)&hbf[idx] = p;
}

// weight slots: 0-6 Wp, 7-48 Wl(l*14+e), 49-90 Wr, 91 Wu, 92 Wv  (93 * 16384 elements)
struct WArgs { const float* Wp; const float* Wl; const float* Wr; const float* Wu; const float* Wv; };
__global__ __launch_bounds__(256) void convw_k(WArgs a, unsigned short* __restrict__ wbf) {
    int i4 = blockIdx.x * 256 + threadIdx.x;
    if (i4 >= 93 * 4096) return;
    int idx = i4 * 4;
    int m = idx >> 14;
    int i = idx & 16383;
    const float* src;
    if (m < 7)       src = a.Wp + (size_t)m * 16384;
    else if (m < 49) src = a.Wl + (size_t)(m - 7) * 16384;
    else if (m < 91) src = a.Wr + (size_t)(m - 49) * 16384;
    else if (m == 91) src = a.Wu;
    else              src = a.Wv;
    float4 v = *(const float4*)&src[i];
    uint2 p;
    p.x = (unsigned)f2bf(v.x) | ((unsigned)f2bf(v.y) << 16);
    p.y = (unsigned)f2bf(v.z) | ((unsigned)f2bf(v.w) << 16);
    *(uint2*)&wbf[idx] = p;
}

// ---------------- fused agg + layer GEMM ----------------
// Per block: 64 slot rows of one edge type.
//   phase 1: wave wv aggregates rows [wv*16, wv*16+16) -> bf16 into LDS As1
//            (quarter-wave per neighbor, identical math to old agg_k)
//   phase 2: wave wv owns cols [wv*32, wv*32+32); W1/W2 col-slices preloaded in regs;
//            A2 (= h[dst] root rows) fragments loaded DIRECTLY from global (contiguous,
//            L2-hot 16KB region) — no LDS staging;
//            acc = As1@W1^T + A2@W2^T (64 MFMA / wave)
//   phase 3: bias, cross-wave l2norm via LDS partial-ss, f16 store to slotb
// LDS = 43008 (As1) + 1024 (ssp) = 44KB -> 3 blocks/CU (12 waves) for gather latency hiding.

#define ACC8(u) do { \
    v[0] += __uint_as_float((u).x << 16); v[1] += __uint_as_float((u).x & 0xFFFF0000u); \
    v[2] += __uint_as_float((u).y << 16); v[3] += __uint_as_float((u).y & 0xFFFF0000u); \
    v[4] += __uint_as_float((u).z << 16); v[5] += __uint_as_float((u).z & 0xFFFF0000u); \
    v[6] += __uint_as_float((u).w << 16); v[7] += __uint_as_float((u).w & 0xFFFF0000u); } while (0)

struct AgArgs {
    int blockPrefix[15];
    const unsigned short* W1[14];
    const unsigned short* W2[14];
    const float* bias[14];
    int cntoff[14];   // slot-row base per edge type
    int dstoff[14];   // h-row base per edge type (A2 root rows)
    int rows[14];
};

__global__ __launch_bounds__(256) void aggemm_k(AgArgs g,
        const int* __restrict__ cnt, const int* __restrict__ cursor,
        const float* __restrict__ inv_deg, const int* __restrict__ colp,
        const unsigned short* __restrict__ hbf, unsigned short* __restrict__ slotb) {
    // row stride 168 shorts = 4 chunks of 40 + 8 pad; chunk c holds elems [c*32, c*32+32)
    __shared__ short As1[64 * 168];
    __shared__ float ssp[64][4];
    int b = blockIdx.x;
    int s = 0;
    while (b >= g.blockPrefix[s + 1]) s++;
    int rows = g.rows[s];
    int row0 = (b - g.blockPrefix[s]) * 64;
    int t = threadIdx.x;
    int wv = t >> 6, lane = t & 63;
    int q = lane >> 4, m15 = lane & 15;
    int cntoff = g.cntoff[s];
    int doff = g.dstoff[s];

    // phase 1: aggregate 16 rows per wave into As1 (bf16, MFMA layout)
    for (int i = 0; i < 16; i++) {
        int lrow = wv * 16 + i;
        int srow = row0 + lrow;
        float v[8];
        #pragma unroll
        for (int ii = 0; ii < 8; ii++) v[ii] = 0.f;
        if (srow < rows) {
            int grow = cntoff + srow;
            int nn = cnt[grow];
            int rs = cursor[grow] - nn;        // cursor==end
            const int* cp = colp + rs;
            int j = 0;
            for (; j + 8 <= nn; j += 8) {
                int c0 = cp[j + q] << 7;
                int c1 = cp[j + 4 + q] << 7;
                uint4 u0 = *(const uint4*)&hbf[c0 + m15 * 8];
                uint4 u1 = *(const uint4*)&hbf[c1 + m15 * 8];
                ACC8(u0);
                ACC8(u1);
            }
            for (; j < nn; j += 4) {
                if (j + q < nn) {
                    int c = cp[j + q] << 7;
                    uint4 u = *(const uint4*)&hbf[c + m15 * 8];
                    ACC8(u);
                }
            }
            float inv = inv_deg[grow];
            #pragma unroll
            for (int ii = 0; ii < 8; ii++) {
                v[ii] += __shfl_xor(v[ii], 16);
                v[ii] += __shfl_xor(v[ii], 32);
                v[ii] *= inv;
            }
        }
        if (q == 0) {   // lane m15 holds elems [m15*8, m15*8+8)
            uint4 o;
            o.x = (unsigned)f2bf(v[0]) | ((unsigned)f2bf(v[1]) << 16);
            o.y = (unsigned)f2bf(v[2]) | ((unsigned)f2bf(v[3]) << 16);
            o.z = (unsigned)f2bf(v[4]) | ((unsigned)f2bf(v[5]) << 16);
            o.w = (unsigned)f2bf(v[6]) | ((unsigned)f2bf(v[7]) << 16);
            *(uint4*)&As1[lrow * 168 + (m15 >> 2) * 40 + (m15 & 3) * 8] = o;
        }
    }

    __builtin_amdgcn_sched_barrier(0);   // keep W preload out of the agg loop
    // W reg preload: this wave's 32 cols x 128 k, both matrices (64 VGPR)
    const uint4* W14 = (const uint4*)g.W1[s];
    const uint4* W24 = (const uint4*)g.W2[s];
    bf16x8 w1r[2][4], w2r[2][4];
    #pragma unroll
    for (int bbl = 0; bbl < 2; bbl++) {
        int colr = ((2 * wv + bbl) * 16 + m15) * 16;   // uint4 index of W row
        #pragma unroll
        for (int kc = 0; kc < 4; kc++) {
            w1r[bbl][kc] = __builtin_bit_cast(bf16x8, W14[colr + kc * 4 + q]);
            w2r[bbl][kc] = __builtin_bit_cast(bf16x8, W24[colr + kc * 4 + q]);
        }
    }
    __syncthreads();

    // phase 2: MFMA — all 64 rows x this wave's 32 cols; A2 fragments direct from global
    const uint4* h4 = (const uint4*)hbf;
    floatx4 acc[4][2];
    #pragma unroll
    for (int m = 0; m < 4; m++) {
        acc[m][0] = (floatx4){0.f, 0.f, 0.f, 0.f};
        acc[m][1] = (floatx4){0.f, 0.f, 0.f, 0.f};
    }
    #pragma unroll
    for (int m = 0; m < 4; m++) {
        int rr = min(row0 + m * 16 + m15, rows - 1);   // clamp tail (dup rows unused)
        size_t hb = (size_t)(doff + rr) * 16;
        bf16x8 a2f[4];
        #pragma unroll
        for (int kc = 0; kc < 4; kc++) a2f[kc] = __builtin_bit_cast(bf16x8, h4[hb + kc * 4 + q]);
        #pragma unroll
        for (int kc = 0; kc < 4; kc++) {
            bf16x8 a1 = __builtin_bit_cast(bf16x8, *(const short8*)&As1[(m * 16 + m15) * 168 + kc * 40 + q * 8]);
            acc[m][0] = __builtin_amdgcn_mfma_f32_16x16x32_bf16(a1, w1r[0][kc], acc[m][0], 0, 0, 0);
            acc[m][1] = __builtin_amdgcn_mfma_f32_16x16x32_bf16(a1, w1r[1][kc], acc[m][1], 0, 0, 0);
            acc[m][0] = __builtin_amdgcn_mfma_f32_16x16x32_bf16(a2f[kc], w2r[0][kc], acc[m][0], 0, 0, 0);
            acc[m][1] = __builtin_amdgcn_mfma_f32_16x16x32_bf16(a2f[kc], w2r[1][kc], acc[m][1], 0, 0, 0);
        }
    }

    // phase 3: bias + cross-wave l2norm + f16 store
    const float* bias = g.bias[s];
    float bv0 = bias[(2 * wv) * 16 + m15];
    float bv1 = bias[(2 * wv + 1) * 16 + m15];
    #pragma unroll
    for (int m = 0; m < 4; m++) {
        #pragma unroll
        for (int reg = 0; reg < 4; reg++) {
            acc[m][0][reg] += bv0;
            acc[m][1][reg] += bv1;
            float ps = acc[m][0][reg] * acc[m][0][reg] + acc[m][1][reg] * acc[m][1][reg];
            ps += __shfl_xor(ps, 1);
            ps += __shfl_xor(ps, 2);
            ps += __shfl_xor(ps, 4);
            ps += __shfl_xor(ps, 8);
            if (m15 == 0) ssp[m * 16 + q * 4 + reg][wv] = ps;
        }
    }
    __syncthreads();
    unsigned short* outp = slotb + (size_t)(cntoff + row0) * HID;
    #pragma unroll
    for (int m = 0; m < 4; m++) {
        #pragma unroll
        for (int reg = 0; reg < 4; reg++) {
            int lr = m * 16 + q * 4 + reg;
            float4 s4 = *(const float4*)&ssp[lr][0];
            float ss = s4.x + s4.y + s4.z + s4.w;
            float sc = 1.0f / fmaxf(sqrtf(ss), 1e-12f);
            if (row0 + lr < rows) {
                unsigned short* o = outp + (size_t)lr * HID;
                o[(2 * wv) * 16 + m15]     = f2h(acc[m][0][reg] * sc);
                o[(2 * wv + 1) * 16 + m15] = f2h(acc[m][1][reg] * sc);
            }
        }
    }
}

// ---------------- MFMA GEMM (input projection / heads) ----------------
struct GemmArgs {
    int blockPrefix[15];
    const unsigned short* A1[14];
    const unsigned short* W1[14];
    const float* bias[14]; void* out[14];
    int rows[14];
};

template<int MODE>
__global__ __launch_bounds__(256) void gemm_k(GemmArgs g) {
    __shared__ short As[64 * 40];
    __shared__ short Ws[128 * 40];
    int b = blockIdx.x;
    int s = 0;
    while (b >= g.blockPrefix[s + 1]) s++;
    int rows = g.rows[s];
    int row0 = (b - g.blockPrefix[s]) * 64;
    int t = threadIdx.x;
    int w = t >> 6, lane = t & 63;
    int q = lane >> 4, m15 = lane & 15;

    floatx4 acc[8];
    #pragma unroll
    for (int bb = 0; bb < 8; bb++) acc[bb] = (floatx4){0.f, 0.f, 0.f, 0.f};

    const uint4* A4 = (const uint4*)g.A1[s];
    const uint4* W4 = (const uint4*)g.W1[s];
    for (int k0 = 0; k0 < 128; k0 += 32) {
        __syncthreads();
        {   // A tile
            int row = t >> 2, kc = t & 3;
            uint4 v = make_uint4(0u, 0u, 0u, 0u);
            if (row0 + row < rows) v = A4[(size_t)(row0 + row) * 16 + (k0 >> 3) + kc];
            *(uint4*)&As[row * 40 + kc * 8] = v;
        }
        #pragma unroll
        for (int i = 0; i < 2; i++) {   // W tile
            int idx = t + i * 256;
            int c = idx >> 2, kc = idx & 3;
            uint4 v = W4[(size_t)c * 16 + (k0 >> 3) + kc];
            *(uint4*)&Ws[c * 40 + kc * 8] = v;
        }
        __syncthreads();
        bf16x8 af = __builtin_bit_cast(bf16x8, *(const short8*)&As[(w * 16 + m15) * 40 + q * 8]);
        #pragma unroll
        for (int bb = 0; bb < 8; bb++) {
            bf16x8 bf = __builtin_bit_cast(bf16x8, *(const short8*)&Ws[(bb * 16 + m15) * 40 + q * 8]);
            acc[bb] = __builtin_amdgcn_mfma_f32_16x16x32_bf16(af, bf, acc[bb], 0, 0, 0);
        }
    }

    const float* bias = g.bias[s];
    #pragma unroll
    for (int bb = 0; bb < 8; bb++) {
        float bv = bias[bb * 16 + m15];
        #pragma unroll
        for (int reg = 0; reg < 4; reg++) acc[bb][reg] += bv;
    }
    if (MODE != 0) {
        #pragma unroll
        for (int reg = 0; reg < 4; reg++) {
            float ss = 0.f;
            #pragma unroll
            for (int bb = 0; bb < 8; bb++) ss += acc[bb][reg] * acc[bb][reg];
            ss += __shfl_xor(ss, 1);
            ss += __shfl_xor(ss, 2);
            ss += __shfl_xor(ss, 4);
            ss += __shfl_xor(ss, 8);
            float sc = 1.0f / fmaxf(sqrtf(ss), 1e-12f);
            #pragma unroll
            for (int bb = 0; bb < 8; bb++) acc[bb][reg] *= sc;
        }
    }
    int rbase = row0 + w * 16 + q * 4;
    if (MODE == 3) {
        float* out = (float*)g.out[s];
        #pragma unroll
        for (int reg = 0; reg < 4; reg++) {
            int r = rbase + reg;
            if (r < rows) {
                float* o = out + (size_t)r * HID;
                #pragma unroll
                for (int bb = 0; bb < 8; bb++) o[bb * 16 + m15] = acc[bb][reg];
            }
        }
    } else {
        unsigned short* out = (unsigned short*)g.out[s];
        #pragma unroll
        for (int reg = 0; reg < 4; reg++) {
            int r = rbase + reg;
            if (r < rows) {
                unsigned short* o = out + (size_t)r * HID;
                #pragma unroll
                for (int bb = 0; bb < 8; bb++) o[bb * 16 + m15] = f2bf(acc[bb][reg]);
            }
        }
    }
}

// ---------------- per-layer update ----------------
__global__ __launch_bounds__(256) void update_k(unsigned short* __restrict__ hbf,
                                                const unsigned short* __restrict__ slotb,
                                                const float* __restrict__ ln_g, const float* __restrict__ ln_b, int l) {
    int row = blockIdx.x * 4 + (threadIdx.x >> 6);
    if (row >= TOTN) return;
    int lane = threadIdx.x & 63;
    int t = 0;
    while (row >= c_NODEPRE[t + 1]) t++;
    int r = row - c_NODEPRE[t];
    int ns = c_UPD_NS[t];
    float s0 = 0.f, s1 = 0.f;
    for (int s = 0; s < ns; s++) {
        const unsigned short* sp = slotb + (size_t)(c_UPD_BASE[t][s] + r) * HID;
        s0 += h2f(sp[lane]);
        s1 += h2f(sp[lane + 64]);
    }
    float invnd = c_INVND[t];
    const float* gg = ln_g + ((size_t)l * 7 + t) * HID;
    const float* bb = ln_b + ((size_t)l * 7 + t) * HID;
    unsigned short* hp = hbf + (size_t)row * HID;
    float x0 = s0 * invnd + bf2f(hp[lane]);
    float x1 = s1 * invnd + bf2f(hp[lane + 64]);
    float s = x0 + x1;
    s += __shfl_xor(s, 1);  s += __shfl_xor(s, 2);  s += __shfl_xor(s, 4);
    s += __shfl_xor(s, 8);  s += __shfl_xor(s, 16); s += __shfl_xor(s, 32);
    float mean = s * (1.0f / 128.0f);
    float d0 = x0 - mean, d1 = x1 - mean;
    float vs = d0 * d0 + d1 * d1;
    vs += __shfl_xor(vs, 1);  vs += __shfl_xor(vs, 2);  vs += __shfl_xor(vs, 4);
    vs += __shfl_xor(vs, 8);  vs += __shfl_xor(vs, 16); vs += __shfl_xor(vs, 32);
    float rstd = rsqrtf(vs * (1.0f / 128.0f) + 1e-5f);
    float y0 = d0 * rstd * gg[lane]      + bb[lane];
    float y1 = d1 * rstd * gg[lane + 64] + bb[lane + 64];
    hp[lane]      = f2bf(fmaxf(y0, 0.f));
    hp[lane + 64] = f2bf(fmaxf(y1, 0.f));
}

// ---------------- host ----------------
extern "C" void kernel_launch(void* const* d_in, const int* in_sizes, int n_in,
                              void* d_out, int out_size, void* d_ws, size_t ws_size,
                              hipStream_t stream) {
    (void)in_sizes; (void)n_in; (void)out_size; (void)ws_size;
    const float* Wp   = (const float*)d_in[21];
    const float* bp   = (const float*)d_in[22];
    const float* Wl   = (const float*)d_in[23];
    const float* bl   = (const float*)d_in[24];
    const float* Wr   = (const float*)d_in[25];
    const float* ln_g = (const float*)d_in[26];
    const float* ln_b = (const float*)d_in[27];
    const float* Wu   = (const float*)d_in[28];
    const float* bu   = (const float*)d_in[29];
    const float* Wv   = (const float*)d_in[30];
    const float* bv   = (const float*)d_in[31];
    float* out = (float*)d_out;

    // d_ws carve (~224.4 MB)
    unsigned short* h_bf   = (unsigned short*)d_ws;                  // TOTN*128 bf16
    unsigned short* w_bf   = h_bf + (size_t)TOTN * HID;              // 93*16384 bf16
    unsigned short* slotb  = w_bf + (size_t)93 * 16384;              // TOTC*128 f16
    int*            cnt    = (int*)(slotb + (size_t)TOTC * HID);     // TOTC
    int*            cursor = cnt + TOTC;                             // TOTC
    float*          invdeg = (float*)(cursor + TOTC);                // TOTC
    unsigned*       pool   = (unsigned*)(invdeg + TOTC);             // TOTE records
    int*            blkHist = (int*)(pool + (size_t)TOTE);           // NBUK*NBLK
    int*            ctrl    = blkHist + (size_t)NBUK * NBLK;         // control block
    int* bktCnt       = ctrl;                 // NBUK
    int* bktEdgeBase  = ctrl + NBUK;          // NBUK+1

    // d_out scratch (overwritten by final head GEMM)
    int* col = (int*)d_out;                                          // TOTE ints

    static const int CNTOFF[14] = {0,40000,140000,143000,183000,203000,243000,263000,303000,311000,351000,411000,451000,454000};
    static const int CNTN[14]   = {40000,100000,3000,40000,20000,40000,20000,40000,8000,40000,60000,40000,3000,60000};
    static const int DSTOFF[14] = {100000,0,140000,100000,143000,100000,143000,100000,163000,100000,171000,100000,231000,171000};
    static const int NODEPRE[8] = {0,100000,140000,143000,163000,171000,231000,234000};
    static const int NT[7]      = {100000,40000,3000,20000,8000,60000,3000};

    EdgeArgs ea;
    for (int e = 0; e < 14; e++) ea.ei[e] = (const int*)d_in[7 + e];

    // CSR build: histogram -> scans -> scatter -> per-bucket fill
    hist_k<<<NBLK, 256, 0, stream>>>(ea, blkHist);
    scan_blk_k<<<NBUK, 256, 0, stream>>>(blkHist, bktCnt);
    scans2_k<<<1, 512, 0, stream>>>(bktCnt, bktEdgeBase);
    scatter_k<<<NBLK, 256, 0, stream>>>(ea, blkHist, bktEdgeBase, pool);
    csrfill_k<<<NBUK, 256, 0, stream>>>(pool, bktEdgeBase, cnt, cursor, invdeg, col);

    {   // conversions
        XArgs xa;
        for (int t = 0; t < 7; t++) xa.x[t] = (const float*)d_in[t];
        convx_k<<<(TOTN * 32 + 255) / 256, 256, 0, stream>>>(xa, h_bf);
        WArgs wa = {Wp, Wl, Wr, Wu, Wv};
        convw_k<<<(93 * 4096 + 255) / 256, 256, 0, stream>>>(wa, w_bf);
    }

    // input projection (in-place bf16): h_bf[t] = x_bf[t] @ Wp[t]^T + bp[t]
    {
        GemmArgs ga;
        int pre = 0; ga.blockPrefix[0] = 0;
        for (int t = 0; t < 7; t++) {
            ga.A1[t] = h_bf + (size_t)NODEPRE[t] * HID;
            ga.W1[t] = w_bf + (size_t)t * 16384;
            ga.bias[t] = bp + (size_t)t * HID;
            ga.out[t] = h_bf + (size_t)NODEPRE[t] * HID;
            ga.rows[t] = NT[t];
            pre += (NT[t] + 63) / 64;
            ga.blockPrefix[t + 1] = pre;
        }
        for (int s = 7; s < 14; s++) { ga.blockPrefix[s + 1] = pre; ga.rows[s] = 0; }
        gemm_k<0><<<pre, 256, 0, stream>>>(ga);
    }

    // layers: one fused aggemm + one update dispatch each
    int agrid;
    AgArgs gl;
    {
        int pre = 0; gl.blockPrefix[0] = 0;
        for (int e = 0; e < 14; e++) {
            gl.rows[e]   = CNTN[e];
            gl.cntoff[e] = CNTOFF[e];
            gl.dstoff[e] = DSTOFF[e];
            pre += (CNTN[e] + 63) / 64;
            gl.blockPrefix[e + 1] = pre;
        }
        agrid = pre;
    }
    for (int l = 0; l < 3; l++) {
        for (int e = 0; e < 14; e++) {
            gl.W1[e]   = w_bf + (size_t)(7  + l * 14 + e) * 16384;
            gl.W2[e]   = w_bf + (size_t)(49 + l * 14 + e) * 16384;
            gl.bias[e] = bl + ((size_t)l * 14 + e) * HID;
        }
        aggemm_k<<<agrid, 256, 0, stream>>>(gl, cnt, cursor, invdeg, col, h_bf, slotb);
        update_k<<<(TOTN + 3) / 4, 256, 0, stream>>>(h_bf, slotb, ln_g, ln_b, l);
    }

    // heads: l2norm(h @ W^T + b) -> fp32 out (overwrites the col scratch in d_out)
    {
        GemmArgs ga;
        ga.blockPrefix[0] = 0;
        ga.A1[0] = h_bf;
        ga.W1[0] = w_bf + (size_t)91 * 16384;
        ga.bias[0] = bu;                        ga.out[0] = out;
        ga.rows[0] = 100000;
        ga.blockPrefix[1] = (100000 + 63) / 64;
        ga.A1[1] = h_bf + (size_t)100000 * HID;
        ga.W1[1] = w_bf + (size_t)92 * 16384;
        ga.bias[1] = bv;                        ga.out[1] = out + (size_t)100000 * HID;
        ga.rows[1] = 40000;
        int tot = ga.blockPrefix[1] + (40000 + 63) / 64;
        for (int s = 2; s < 14; s++) { ga.blockPrefix[s + 1] = tot; ga.rows[s] = 0; }
        ga.blockPrefix[2] = tot;
        gemm_k<3><<<tot, 256, 0, stream>>>(ga);
    }
}

// Round 5
// 2169.839 us; speedup vs baseline: 1.0615x; 1.0615x over previous
//
#include <hip/hip_runtime.h>
#include <math.h>

// ---------------- compile-time problem constants ----------------
#define TOTE 5400000   // total edges
#define TOTN 234000    // total node rows (all types concatenated)
#define TOTC 514000    // total dst slots over 14 edge types
#define HID  128

// bucketed CSR build (two-pass stable binning, no global atomics)
#define NBUK 499        // coarse dst-range buckets over all 14 edge types (span <= 2048 slots)
#define NBLK 1024       // blocks in hist_k / scatter_k (NBLK == 256*4 for scan_blk_k)

// ws carve (~224.4 MB, proven-safe ceiling 245.8 MB)
// d_out scratch: col (21.6MB), overwritten by the head GEMM at the end.

typedef __attribute__((ext_vector_type(8))) short short8;
typedef __attribute__((ext_vector_type(8))) __bf16 bf16x8;
typedef __attribute__((ext_vector_type(4))) float floatx4;

__constant__ int c_EPRE[15]   = {0,1000000,2000000,2500000,3000000,3200000,3400000,3600000,3800000,3900000,4000000,4300000,4600000,5000000,5400000};
__constant__ int c_ECNT[14]   = {1000000,1000000,500000,500000,200000,200000,200000,200000,100000,100000,300000,300000,400000,400000};
__constant__ int c_CNTOFF[14] = {0,40000,140000,143000,183000,203000,243000,263000,303000,311000,351000,411000,451000,454000};
__constant__ int c_CNTN[14]   = {40000,100000,3000,40000,20000,40000,20000,40000,8000,40000,60000,40000,3000,60000};
__constant__ int c_SRCOFF[14] = {0,100000,100000,140000,100000,143000,100000,143000,100000,163000,100000,171000,171000,231000};
__constant__ int c_NODEPRE[8] = {0,100000,140000,143000,163000,171000,231000,234000};
__constant__ float c_INVND[7] = {1.0f, 1.0f/6.0f, 1.0f, 0.5f, 1.0f, 0.5f, 1.0f};
// slot ranges feeding each dst node type (for update_k)
__constant__ int c_UPD_NS[7]      = {1,6,1,2,1,2,1};
__constant__ int c_UPD_BASE[7][6] = {
    {40000,0,0,0,0,0},
    {0,143000,203000,263000,311000,411000},
    {140000,0,0,0,0,0},
    {183000,243000,0,0,0,0},
    {303000,0,0,0,0,0},
    {351000,454000,0,0,0,0},
    {451000,0,0,0,0,0}};
// bucket tables: per-type dst shift and bucket-id base (prefix of ceil(CNTN/2^sh))
__constant__ int c_BSH[14]   = {9,10,6,10,10,11,10,11,10,11,11,11,6,11};
__constant__ int c_BBASE[15] = {0,79,177,224,264,284,304,324,344,352,372,402,422,469,499};

static __device__ __forceinline__ unsigned short f2bf(float f) {
    unsigned u = __float_as_uint(f);
    u = u + 0x7FFFu + ((u >> 16) & 1u);
    return (unsigned short)(u >> 16);
}
static __device__ __forceinline__ float bf2f(unsigned short s) {
    return __uint_as_float(((unsigned)s) << 16);
}
static __device__ __forceinline__ unsigned short f2h(float f) {
    _Float16 h = (_Float16)f;
    return __builtin_bit_cast(unsigned short, h);
}
static __device__ __forceinline__ float h2f(unsigned short s) {
    _Float16 h = __builtin_bit_cast(_Float16, s);
    return (float)h;
}

struct EdgeArgs { const int* ei[14]; };

// ---------------- CSR build: stable two-pass binning ----------------
// Record: (slot_local:11 | src_global:18), < 2^29.

__global__ __launch_bounds__(256) void hist_k(EdgeArgs a, int* __restrict__ blkHist) {
    __shared__ int h[NBUK];
    int t = threadIdx.x;
    for (int i = t; i < NBUK; i += 256) h[i] = 0;
    __syncthreads();
    const int per = (TOTE + NBLK - 1) / NBLK;
    int s = blockIdx.x * per;
    int eEnd = min(s + per, TOTE);
    for (int g = s + t; g < eEnd; g += 256) {
        int e = 0;
        while (g >= c_EPRE[e + 1]) e++;
        int k = g - c_EPRE[e];
        int dst = a.ei[e][c_ECNT[e] + k];
        atomicAdd(&h[c_BBASE[e] + (dst >> c_BSH[e])], 1);
    }
    __syncthreads();
    for (int i = t; i < NBUK; i += 256) blkHist[(size_t)i * NBLK + blockIdx.x] = h[i];
}

__global__ __launch_bounds__(256) void scan_blk_k(int* __restrict__ blkHist, int* __restrict__ bktCnt) {
    int b = blockIdx.x;
    int* p = blkHist + (size_t)b * NBLK;
    int t = threadIdx.x;
    int4 v = *(int4*)&p[t * 4];
    int s = v.x + v.y + v.z + v.w;
    int lane = t & 63, w = t >> 6;
    __shared__ int wt[4];
    int incl = s;
    #pragma unroll
    for (int d = 1; d < 64; d <<= 1) { int o = __shfl_up(incl, d); if (lane >= d) incl += o; }
    if (lane == 63) wt[w] = incl;
    __syncthreads();
    int wb = 0;
    for (int i = 0; i < w; i++) wb += wt[i];
    int excl = incl - s + wb;
    int4 o;
    o.x = excl; o.y = excl + v.x; o.z = excl + v.x + v.y; o.w = excl + v.x + v.y + v.z;
    *(int4*)&p[t * 4] = o;
    if (t == 255) bktCnt[b] = excl + s;
}

__global__ __launch_bounds__(512) void scans2_k(const int* __restrict__ bktCnt, int* __restrict__ bktEdgeBase) {
    int t = threadIdx.x;
    int v = (t < NBUK) ? bktCnt[t] : 0;
    int lane = t & 63, w = t >> 6;
    __shared__ int wt[8];
    int incl = v;
    #pragma unroll
    for (int d = 1; d < 64; d <<= 1) { int o = __shfl_up(incl, d); if (lane >= d) incl += o; }
    if (lane == 63) wt[w] = incl;
    __syncthreads();
    int wb = 0;
    for (int i = 0; i < w; i++) wb += wt[i];
    int excl = incl - v + wb;
    if (t < NBUK) bktEdgeBase[t] = excl;
    if (t == NBUK - 1) bktEdgeBase[NBUK] = excl + v;
}

__global__ __launch_bounds__(256) void scatter_k(EdgeArgs a, const int* __restrict__ blkHist,
        const int* __restrict__ bktEdgeBase, unsigned* __restrict__ pool) {
    __shared__ int cur[NBUK];
    int t = threadIdx.x;
    for (int i = t; i < NBUK; i += 256)
        cur[i] = bktEdgeBase[i] + blkHist[(size_t)i * NBLK + blockIdx.x];
    __syncthreads();
    const int per = (TOTE + NBLK - 1) / NBLK;
    int s = blockIdx.x * per;
    int eEnd = min(s + per, TOTE);
    for (int g = s + t; g < eEnd; g += 256) {
        int e = 0;
        while (g >= c_EPRE[e + 1]) e++;
        int k = g - c_EPRE[e];
        int src = a.ei[e][k];
        int dst = a.ei[e][c_ECNT[e] + k];
        int sh = c_BSH[e];
        unsigned rec = ((unsigned)(dst & ((1 << sh) - 1)) << 18) | (unsigned)(c_SRCOFF[e] + src);
        int p = atomicAdd(&cur[c_BBASE[e] + (dst >> sh)], 1);
        pool[p] = rec;
    }
}

__global__ __launch_bounds__(256) void csrfill_k(
        const unsigned* __restrict__ pool, const int* __restrict__ bktEdgeBase,
        int* __restrict__ cnt, int* __restrict__ cursor, float* __restrict__ invdeg,
        int* __restrict__ col) {
    __shared__ int hist[2048];
    __shared__ int cur[2048];
    __shared__ int wtot[4];
    __shared__ int wbase[4];
    int b = blockIdx.x;
    int t = threadIdx.x;
    int e = 0;
    while (b >= c_BBASE[e + 1]) e++;
    int lb = b - c_BBASE[e];
    int sh = c_BSH[e];
    int s0t = lb << sh;
    int span = min(1 << sh, c_CNTN[e] - s0t);
    int gs0 = c_CNTOFF[e] + s0t;
    int ebase = bktEdgeBase[b];
    int nrec = bktEdgeBase[b + 1] - ebase;

    for (int i = t; i < span; i += 256) hist[i] = 0;
    __syncthreads();
    for (int i = t; i < nrec; i += 256) atomicAdd(&hist[pool[ebase + i] >> 18], 1);
    __syncthreads();
    int base = t * 8, loc = 0, lv[8];
    #pragma unroll
    for (int i = 0; i < 8; i++) {
        int ii = base + i;
        int v = (ii < span) ? hist[ii] : 0;
        lv[i] = loc; loc += v;
    }
    int lane = t & 63, w = t >> 6;
    int incl = loc;
    #pragma unroll
    for (int d = 1; d < 64; d <<= 1) { int o = __shfl_up(incl, d); if (lane >= d) incl += o; }
    if (lane == 63) wtot[w] = incl;
    __syncthreads();
    if (t == 0) { int s2 = 0; for (int i = 0; i < 4; i++) { wbase[i] = s2; s2 += wtot[i]; } }
    __syncthreads();
    int texcl = incl - loc + wbase[w];
    #pragma unroll
    for (int i = 0; i < 8; i++) {
        int ii = base + i;
        if (ii < span) cur[ii] = texcl + lv[i];
    }
    __syncthreads();
    for (int i = t; i < span; i += 256) {
        int c = hist[i];
        cnt[gs0 + i] = c;
        cursor[gs0 + i] = ebase + cur[i] + c;     // end semantics
        invdeg[gs0 + i] = 1.0f / fmaxf((float)c, 1.0f);
    }
    __syncthreads();
    for (int i = t; i < nrec; i += 256) {
        unsigned rec = pool[ebase + i];
        int p = atomicAdd(&cur[rec >> 18], 1);
        col[ebase + p] = (int)(rec & 0x3FFFFu);
    }
}

// ---------------- conversions ----------------
struct XArgs { const float* x[7]; };
__global__ __launch_bounds__(256) void convx_k(XArgs a, unsigned short* __restrict__ hbf) {
    int i4 = blockIdx.x * 256 + threadIdx.x;
    if (i4 >= TOTN * 32) return;           // float4 index
    int idx = i4 * 4;
    int t = 0;
    while (idx >= c_NODEPRE[t + 1] * 128) t++;
    float4 v = *(const float4*)&a.x[t][idx - c_NODEPRE[t] * 128];
    uint2 p;
    p.x = (unsigned)f2bf(v.x) | ((unsigned)f2bf(v.y) << 16);
    p.y = (unsigned)f2bf(v.z) | ((unsigned)f2bf(v.w) << 16);
    *(uint2*)&hbf[idx] = p;
}

// weight slots: 0-6 Wp, 7-48 Wl(l*14+e), 49-90 Wr, 91 Wu, 92 Wv  (93 * 16384 elements)
struct WArgs { const float* Wp; const float* Wl; const float* Wr; const float* Wu; const float* Wv; };
__global__ __launch_bounds__(256) void convw_k(WArgs a, unsigned short* __restrict__ wbf) {
    int i4 = blockIdx.x * 256 + threadIdx.x;
    if (i4 >= 93 * 4096) return;
    int idx = i4 * 4;
    int m = idx >> 14;
    int i = idx & 16383;
    const float* src;
    if (m < 7)       src = a.Wp + (size_t)m * 16384;
    else if (m < 49) src = a.Wl + (size_t)(m - 7) * 16384;
    else if (m < 91) src = a.Wr + (size_t)(m - 49) * 16384;
    else if (m == 91) src = a.Wu;
    else              src = a.Wv;
    float4 v = *(const float4*)&src[i];
    uint2 p;
    p.x = (unsigned)f2bf(v.x) | ((unsigned)f2bf(v.y) << 16);
    p.y = (unsigned)f2bf(v.z) | ((unsigned)f2bf(v.w) << 16);
    *(uint2*)&wbf[idx] = p;
}

// ---------------- fused agg + layer GEMM ----------------
// Per block: 64 slot rows of one edge type.
//   phase 1: wave wv aggregates rows [wv*16, wv*16+16) -> bf16 into LDS As1
//   phase 2: wave wv owns cols [wv*32, wv*32+32); W1/W2 fragments STREAMED from
//            global inside the kc loop (L1/L2-hot, MfmaUtil has 40x headroom);
//            A2 (= h[dst] root rows) fragments loaded directly from global;
//            acc = As1@W1^T + A2@W2^T (64 MFMA / wave)
//   phase 3: bias, cross-wave l2norm via LDS partial-ss, f16 store to slotb
// __launch_bounds__(256,5): cap ~102 VGPR -> 5 waves/SIMD (20/CU) so the
// latency-bound gather keeps enough resident waves (round-4 lesson: 192 regs
// -> 33% occupancy -> gather rate halved).

#define ACC8(u) do { \
    v[0] += __uint_as_float((u).x << 16); v[1] += __uint_as_float((u).x & 0xFFFF0000u); \
    v[2] += __uint_as_float((u).y << 16); v[3] += __uint_as_float((u).y & 0xFFFF0000u); \
    v[4] += __uint_as_float((u).z << 16); v[5] += __uint_as_float((u).z & 0xFFFF0000u); \
    v[6] += __uint_as_float((u).w << 16); v[7] += __uint_as_float((u).w & 0xFFFF0000u); } while (0)

struct AgArgs {
    int blockPrefix[15];
    const unsigned short* W1[14];
    const unsigned short* W2[14];
    const float* bias[14];
    int cntoff[14];   // slot-row base per edge type
    int dstoff[14];   // h-row base per edge type (A2 root rows)
    int rows[14];
};

__global__ __launch_bounds__(256, 5) void aggemm_k(AgArgs g,
        const int* __restrict__ cnt, const int* __restrict__ cursor,
        const float* __restrict__ inv_deg, const int* __restrict__ colp,
        const unsigned short* __restrict__ hbf, unsigned short* __restrict__ slotb) {
    // row stride 168 shorts = 4 chunks of 40 + 8 pad; chunk c holds elems [c*32, c*32+32)
    __shared__ short As1[64 * 168];
    __shared__ float ssp[64][4];
    int b = blockIdx.x;
    int s = 0;
    while (b >= g.blockPrefix[s + 1]) s++;
    int rows = g.rows[s];
    int row0 = (b - g.blockPrefix[s]) * 64;
    int t = threadIdx.x;
    int wv = t >> 6, lane = t & 63;
    int q = lane >> 4, m15 = lane & 15;
    int cntoff = g.cntoff[s];
    int doff = g.dstoff[s];

    // phase 1: aggregate 16 rows per wave into As1 (bf16, MFMA layout)
    for (int i = 0; i < 16; i++) {
        int lrow = wv * 16 + i;
        int srow = row0 + lrow;
        float v[8];
        #pragma unroll
        for (int ii = 0; ii < 8; ii++) v[ii] = 0.f;
        if (srow < rows) {
            int grow = cntoff + srow;
            int nn = cnt[grow];
            int rs = cursor[grow] - nn;        // cursor==end
            const int* cp = colp + rs;
            int j = 0;
            for (; j + 8 <= nn; j += 8) {
                int c0 = cp[j + q] << 7;
                int c1 = cp[j + 4 + q] << 7;
                uint4 u0 = *(const uint4*)&hbf[c0 + m15 * 8];
                uint4 u1 = *(const uint4*)&hbf[c1 + m15 * 8];
                ACC8(u0);
                ACC8(u1);
            }
            for (; j < nn; j += 4) {
                if (j + q < nn) {
                    int c = cp[j + q] << 7;
                    uint4 u = *(const uint4*)&hbf[c + m15 * 8];
                    ACC8(u);
                }
            }
            float inv = inv_deg[grow];
            #pragma unroll
            for (int ii = 0; ii < 8; ii++) {
                v[ii] += __shfl_xor(v[ii], 16);
                v[ii] += __shfl_xor(v[ii], 32);
                v[ii] *= inv;
            }
        }
        if (q == 0) {   // lane m15 holds elems [m15*8, m15*8+8)
            uint4 o;
            o.x = (unsigned)f2bf(v[0]) | ((unsigned)f2bf(v[1]) << 16);
            o.y = (unsigned)f2bf(v[2]) | ((unsigned)f2bf(v[3]) << 16);
            o.z = (unsigned)f2bf(v[4]) | ((unsigned)f2bf(v[5]) << 16);
            o.w = (unsigned)f2bf(v[6]) | ((unsigned)f2bf(v[7]) << 16);
            *(uint4*)&As1[lrow * 168 + (m15 >> 2) * 40 + (m15 & 3) * 8] = o;
        }
    }
    __syncthreads();

    // phase 2: MFMA — all 64 rows x this wave's 32 cols; W and A2 streamed from global
    const uint4* W14 = (const uint4*)g.W1[s];
    const uint4* W24 = (const uint4*)g.W2[s];
    const uint4* h4 = (const uint4*)hbf;
    int colr0 = ((2 * wv) * 16 + m15) * 16;        // uint4 index of W row (bbl 0)
    int colr1 = colr0 + 256;                       // +16 rows
    floatx4 acc[4][2];
    #pragma unroll
    for (int m = 0; m < 4; m++) {
        acc[m][0] = (floatx4){0.f, 0.f, 0.f, 0.f};
        acc[m][1] = (floatx4){0.f, 0.f, 0.f, 0.f};
    }
    #pragma unroll
    for (int kc = 0; kc < 4; kc++) {
        int ko = kc * 4 + q;
        bf16x8 w10 = __builtin_bit_cast(bf16x8, W14[colr0 + ko]);
        bf16x8 w11 = __builtin_bit_cast(bf16x8, W14[colr1 + ko]);
        bf16x8 w20 = __builtin_bit_cast(bf16x8, W24[colr0 + ko]);
        bf16x8 w21 = __builtin_bit_cast(bf16x8, W24[colr1 + ko]);
        #pragma unroll
        for (int m = 0; m < 4; m++) {
            int rr = min(row0 + m * 16 + m15, rows - 1);   // clamp tail (dup rows unused)
            bf16x8 a2 = __builtin_bit_cast(bf16x8, h4[(size_t)(doff + rr) * 16 + ko]);
            bf16x8 a1 = __builtin_bit_cast(bf16x8, *(const short8*)&As1[(m * 16 + m15) * 168 + kc * 40 + q * 8]);
            acc[m][0] = __builtin_amdgcn_mfma_f32_16x16x32_bf16(a1, w10, acc[m][0], 0, 0, 0);
            acc[m][1] = __builtin_amdgcn_mfma_f32_16x16x32_bf16(a1, w11, acc[m][1], 0, 0, 0);
            acc[m][0] = __builtin_amdgcn_mfma_f32_16x16x32_bf16(a2, w20, acc[m][0], 0, 0, 0);
            acc[m][1] = __builtin_amdgcn_mfma_f32_16x16x32_bf16(a2, w21, acc[m][1], 0, 0, 0);
        }
    }

    // phase 3: bias + cross-wave l2norm + f16 store
    const float* bias = g.bias[s];
    float bv0 = bias[(2 * wv) * 16 + m15];
    float bv1 = bias[(2 * wv + 1) * 16 + m15];
    #pragma unroll
    for (int m = 0; m < 4; m++) {
        #pragma unroll
        for (int reg = 0; reg < 4; reg++) {
            acc[m][0][reg] += bv0;
            acc[m][1][reg] += bv1;
            float ps = acc[m][0][reg] * acc[m][0][reg] + acc[m][1][reg] * acc[m][1][reg];
            ps += __shfl_xor(ps, 1);
            ps += __shfl_xor(ps, 2);
            ps += __shfl_xor(ps, 4);
            ps += __shfl_xor(ps, 8);
            if (m15 == 0) ssp[m * 16 + q * 4 + reg][wv] = ps;
        }
    }
    __syncthreads();
    unsigned short* outp = slotb + (size_t)(cntoff + row0) * HID;
    #pragma unroll
    for (int m = 0; m < 4; m++) {
        #pragma unroll
        for (int reg = 0; reg < 4; reg++) {
            int lr = m * 16 + q * 4 + reg;
            float4 s4 = *(const float4*)&ssp[lr][0];
            float ss = s4.x + s4.y + s4.z + s4.w;
            float sc = 1.0f / fmaxf(sqrtf(ss), 1e-12f);
            if (row0 + lr < rows) {
                unsigned short* o = outp + (size_t)lr * HID;
                o[(2 * wv) * 16 + m15]     = f2h(acc[m][0][reg] * sc);
                o[(2 * wv + 1) * 16 + m15] = f2h(acc[m][1][reg] * sc);
            }
        }
    }
}

// ---------------- MFMA GEMM (input projection / heads) ----------------
struct GemmArgs {
    int blockPrefix[15];
    const unsigned short* A1[14];
    const unsigned short* W1[14];
    const float* bias[14]; void* out[14];
    int rows[14];
};

template<int MODE>
__global__ __launch_bounds__(256) void gemm_k(GemmArgs g) {
    __shared__ short As[64 * 40];
    __shared__ short Ws[128 * 40];
    int b = blockIdx.x;
    int s = 0;
    while (b >= g.blockPrefix[s + 1]) s++;
    int rows = g.rows[s];
    int row0 = (b - g.blockPrefix[s]) * 64;
    int t = threadIdx.x;
    int w = t >> 6, lane = t & 63;
    int q = lane >> 4, m15 = lane & 15;

    floatx4 acc[8];
    #pragma unroll
    for (int bb = 0; bb < 8; bb++) acc[bb] = (floatx4){0.f, 0.f, 0.f, 0.f};

    const uint4* A4 = (const uint4*)g.A1[s];
    const uint4* W4 = (const uint4*)g.W1[s];
    for (int k0 = 0; k0 < 128; k0 += 32) {
        __syncthreads();
        {   // A tile
            int row = t >> 2, kc = t & 3;
            uint4 v = make_uint4(0u, 0u, 0u, 0u);
            if (row0 + row < rows) v = A4[(size_t)(row0 + row) * 16 + (k0 >> 3) + kc];
            *(uint4*)&As[row * 40 + kc * 8] = v;
        }
        #pragma unroll
        for (int i = 0; i < 2; i++) {   // W tile
            int idx = t + i * 256;
            int c = idx >> 2, kc = idx & 3;
            uint4 v = W4[(size_t)c * 16 + (k0 >> 3) + kc];
            *(uint4*)&Ws[c * 40 + kc * 8] = v;
        }
        __syncthreads();
        bf16x8 af = __builtin_bit_cast(bf16x8, *(const short8*)&As[(w * 16 + m15) * 40 + q * 8]);
        #pragma unroll
        for (int bb = 0; bb < 8; bb++) {
            bf16x8 bf = __builtin_bit_cast(bf16x8, *(const short8*)&Ws[(bb * 16 + m15) * 40 + q * 8]);
            acc[bb] = __builtin_amdgcn_mfma_f32_16x16x32_bf16(af, bf, acc[bb], 0, 0, 0);
        }
    }

    const float* bias = g.bias[s];
    #pragma unroll
    for (int bb = 0; bb < 8; bb++) {
        float bv = bias[bb * 16 + m15];
        #pragma unroll
        for (int reg = 0; reg < 4; reg++) acc[bb][reg] += bv;
    }
    if (MODE != 0) {
        #pragma unroll
        for (int reg = 0; reg < 4; reg++) {
            float ss = 0.f;
            #pragma unroll
            for (int bb = 0; bb < 8; bb++) ss += acc[bb][reg] * acc[bb][reg];
            ss += __shfl_xor(ss, 1);
            ss += __shfl_xor(ss, 2);
            ss += __shfl_xor(ss, 4);
            ss += __shfl_xor(ss, 8);
            float sc = 1.0f / fmaxf(sqrtf(ss), 1e-12f);
            #pragma unroll
            for (int bb = 0; bb < 8; bb++) acc[bb][reg] *= sc;
        }
    }
    int rbase = row0 + w * 16 + q * 4;
    if (MODE == 3) {
        float* out = (float*)g.out[s];
        #pragma unroll
        for (int reg = 0; reg < 4; reg++) {
            int r = rbase + reg;
            if (r < rows) {
                float* o = out + (size_t)r * HID;
                #pragma unroll
                for (int bb = 0; bb < 8; bb++) o[bb * 16 + m15] = acc[bb][reg];
            }
        }
    } else {
        unsigned short* out = (unsigned short*)g.out[s];
        #pragma unroll
        for (int reg = 0; reg < 4; reg++) {
            int r = rbase + reg;
            if (r < rows) {
                unsigned short* o = out + (size_t)r * HID;
                #pragma unroll
                for (int bb = 0; bb < 8; bb++) o[bb * 16 + m15] = f2bf(acc[bb][reg]);
            }
        }
    }
}

// ---------------- per-layer update ----------------
__global__ __launch_bounds__(256) void update_k(unsigned short* __restrict__ hbf,
                                                const unsigned short* __restrict__ slotb,
                                                const float* __restrict__ ln_g, const float* __restrict__ ln_b, int l) {
    int row = blockIdx.x * 4 + (threadIdx.x >> 6);
    if (row >= TOTN) return;
    int lane = threadIdx.x & 63;
    int t = 0;
    while (row >= c_NODEPRE[t + 1]) t++;
    int r = row - c_NODEPRE[t];
    int ns = c_UPD_NS[t];
    float s0 = 0.f, s1 = 0.f;
    for (int s = 0; s < ns; s++) {
        const unsigned short* sp = slotb + (size_t)(c_UPD_BASE[t][s] + r) * HID;
        s0 += h2f(sp[lane]);
        s1 += h2f(sp[lane + 64]);
    }
    float invnd = c_INVND[t];
    const float* gg = ln_g + ((size_t)l * 7 + t) * HID;
    const float* bb = ln_b + ((size_t)l * 7 + t) * HID;
    unsigned short* hp = hbf + (size_t)row * HID;
    float x0 = s0 * invnd + bf2f(hp[lane]);
    float x1 = s1 * invnd + bf2f(hp[lane + 64]);
    float s = x0 + x1;
    s += __shfl_xor(s, 1);  s += __shfl_xor(s, 2);  s += __shfl_xor(s, 4);
    s += __shfl_xor(s, 8);  s += __shfl_xor(s, 16); s += __shfl_xor(s, 32);
    float mean = s * (1.0f / 128.0f);
    float d0 = x0 - mean, d1 = x1 - mean;
    float vs = d0 * d0 + d1 * d1;
    vs += __shfl_xor(vs, 1);  vs += __shfl_xor(vs, 2);  vs += __shfl_xor(vs, 4);
    vs += __shfl_xor(vs, 8);  vs += __shfl_xor(vs, 16); vs += __shfl_xor(vs, 32);
    float rstd = rsqrtf(vs * (1.0f / 128.0f) + 1e-5f);
    float y0 = d0 * rstd * gg[lane]      + bb[lane];
    float y1 = d1 * rstd * gg[lane + 64] + bb[lane + 64];
    hp[lane]      = f2bf(fmaxf(y0, 0.f));
    hp[lane + 64] = f2bf(fmaxf(y1, 0.f));
}

// ---------------- host ----------------
extern "C" void kernel_launch(void* const* d_in, const int* in_sizes, int n_in,
                              void* d_out, int out_size, void* d_ws, size_t ws_size,
                              hipStream_t stream) {
    (void)in_sizes; (void)n_in; (void)out_size; (void)ws_size;
    const float* Wp   = (const float*)d_in[21];
    const float* bp   = (const float*)d_in[22];
    const float* Wl   = (const float*)d_in[23];
    const float* bl   = (const float*)d_in[24];
    const float* Wr   = (const float*)d_in[25];
    const float* ln_g = (const float*)d_in[26];
    const float* ln_b = (const float*)d_in[27];
    const float* Wu   = (const float*)d_in[28];
    const float* bu   = (const float*)d_in[29];
    const float* Wv   = (const float*)d_in[30];
    const float* bv   = (const float*)d_in[31];
    float* out = (float*)d_out;

    // d_ws carve (~224.4 MB)
    unsigned short* h_bf   = (unsigned short*)d_ws;                  // TOTN*128 bf16
    unsigned short* w_bf   = h_bf + (size_t)TOTN * HID;              // 93*16384 bf16
    unsigned short* slotb  = w_bf + (size_t)93 * 16384;              // TOTC*128 f16
    int*            cnt    = (int*)(slotb + (size_t)TOTC * HID);     // TOTC
    int*            cursor = cnt + TOTC;                             // TOTC
    float*          invdeg = (float*)(cursor + TOTC);                // TOTC
    unsigned*       pool   = (unsigned*)(invdeg + TOTC);             // TOTE records
    int*            blkHist = (int*)(pool + (size_t)TOTE);           // NBUK*NBLK
    int*            ctrl    = blkHist + (size_t)NBUK * NBLK;         // control block
    int* bktCnt       = ctrl;                 // NBUK
    int* bktEdgeBase  = ctrl + NBUK;          // NBUK+1

    // d_out scratch (overwritten by final head GEMM)
    int* col = (int*)d_out;                                          // TOTE ints

    static const int CNTOFF[14] = {0,40000,140000,143000,183000,203000,243000,263000,303000,311000,351000,411000,451000,454000};
    static const int CNTN[14]   = {40000,100000,3000,40000,20000,40000,20000,40000,8000,40000,60000,40000,3000,60000};
    static const int DSTOFF[14] = {100000,0,140000,100000,143000,100000,143000,100000,163000,100000,171000,100000,231000,171000};
    static const int NODEPRE[8] = {0,100000,140000,143000,163000,171000,231000,234000};
    static const int NT[7]      = {100000,40000,3000,20000,8000,60000,3000};

    EdgeArgs ea;
    for (int e = 0; e < 14; e++) ea.ei[e] = (const int*)d_in[7 + e];

    // CSR build: histogram -> scans -> scatter -> per-bucket fill
    hist_k<<<NBLK, 256, 0, stream>>>(ea, blkHist);
    scan_blk_k<<<NBUK, 256, 0, stream>>>(blkHist, bktCnt);
    scans2_k<<<1, 512, 0, stream>>>(bktCnt, bktEdgeBase);
    scatter_k<<<NBLK, 256, 0, stream>>>(ea, blkHist, bktEdgeBase, pool);
    csrfill_k<<<NBUK, 256, 0, stream>>>(pool, bktEdgeBase, cnt, cursor, invdeg, col);

    {   // conversions
        XArgs xa;
        for (int t = 0; t < 7; t++) xa.x[t] = (const float*)d_in[t];
        convx_k<<<(TOTN * 32 + 255) / 256, 256, 0, stream>>>(xa, h_bf);
        WArgs wa = {Wp, Wl, Wr, Wu, Wv};
        convw_k<<<(93 * 4096 + 255) / 256, 256, 0, stream>>>(wa, w_bf);
    }

    // input projection (in-place bf16): h_bf[t] = x_bf[t] @ Wp[t]^T + bp[t]
    {
        GemmArgs ga;
        int pre = 0; ga.blockPrefix[0] = 0;
        for (int t = 0; t < 7; t++) {
            ga.A1[t] = h_bf + (size_t)NODEPRE[t] * HID;
            ga.W1[t] = w_bf + (size_t)t * 16384;
            ga.bias[t] = bp + (size_t)t * HID;
            ga.out[t] = h_bf + (size_t)NODEPRE[t] * HID;
            ga.rows[t] = NT[t];
            pre += (NT[t] + 63) / 64;
            ga.blockPrefix[t + 1] = pre;
        }
        for (int s = 7; s < 14; s++) { ga.blockPrefix[s + 1] = pre; ga.rows[s] = 0; }
        gemm_k<0><<<pre, 256, 0, stream>>>(ga);
    }

    // layers: one fused aggemm + one update dispatch each
    int agrid;
    AgArgs gl;
    {
        int pre = 0; gl.blockPrefix[0] = 0;
        for (int e = 0; e < 14; e++) {
            gl.rows[e]   = CNTN[e];
            gl.cntoff[e] = CNTOFF[e];
            gl.dstoff[e] = DSTOFF[e];
            pre += (CNTN[e] + 63) / 64;
            gl.blockPrefix[e + 1] = pre;
        }
        agrid = pre;
    }
    for (int l = 0; l < 3; l++) {
        for (int e = 0; e < 14; e++) {
            gl.W1[e]   = w_bf + (size_t)(7  + l * 14 + e) * 16384;
            gl.W2[e]   = w_bf + (size_t)(49 + l * 14 + e) * 16384;
            gl.bias[e] = bl + ((size_t)l * 14 + e) * HID;
        }
        aggemm_k<<<agrid, 256, 0, stream>>>(gl, cnt, cursor, invdeg, col, h_bf, slotb);
        update_k<<<(TOTN + 3) / 4, 256, 0, stream>>>(h_bf, slotb, ln_g, ln_b, l);
    }

    // heads: l2norm(h @ W^T + b) -> fp32 out (overwrites the col scratch in d_out)
    {
        GemmArgs ga;
        ga.blockPrefix[0] = 0;
        ga.A1[0] = h_bf;
        ga.W1[0] = w_bf + (size_t)91 * 16384;
        ga.bias[0] = bu;                        ga.out[0] = out;
        ga.rows[0] = 100000;
        ga.blockPrefix[1] = (100000 + 63) / 64;
        ga.A1[1] = h_bf + (size_t)100000 * HID;
        ga.W1[1] = w_bf + (size_t)92 * 16384;
        ga.bias[1] = bv;                        ga.out[1] = out + (size_t)100000 * HID;
        ga.rows[1] = 40000;
        int tot = ga.blockPrefix[1] + (40000 + 63) / 64;
        for (int s = 2; s < 14; s++) { ga.blockPrefix[s + 1] = tot; ga.rows[s] = 0; }
        ga.blockPrefix[2] = tot;
        gemm_k<3><<<tot, 256, 0, stream>>>(ga);
    }
}

// Round 6
// 1597.748 us; speedup vs baseline: 1.4416x; 1.3581x over previous
//
#include <hip/hip_runtime.h>
#include <math.h>

// ---------------- compile-time problem constants ----------------
#define TOTE 5400000   // total edges
#define TOTN 234000    // total node rows (all types concatenated)
#define TOTC 514000    // total dst slots over 14 edge types
#define HID  128

// bucketed CSR build (two-pass stable binning, no global atomics)
#define NBUK 499        // coarse dst-range buckets over all 14 edge types (span <= 2048 slots)
#define NBLK 1024       // blocks in hist_k / scatter_k (NBLK == 256*4 for scan_blk_k)

// ws carve (~224.4 MB, proven-safe ceiling 245.8 MB)
// d_out scratch: col (21.6MB), overwritten by the head GEMM at the end.

typedef __attribute__((ext_vector_type(8))) short short8;
typedef __attribute__((ext_vector_type(8))) __bf16 bf16x8;
typedef __attribute__((ext_vector_type(4))) float floatx4;
typedef __attribute__((ext_vector_type(2))) float float2v;

__constant__ int c_EPRE[15]   = {0,1000000,2000000,2500000,3000000,3200000,3400000,3600000,3800000,3900000,4000000,4300000,4600000,5000000,5400000};
__constant__ int c_ECNT[14]   = {1000000,1000000,500000,500000,200000,200000,200000,200000,100000,100000,300000,300000,400000,400000};
__constant__ int c_CNTOFF[14] = {0,40000,140000,143000,183000,203000,243000,263000,303000,311000,351000,411000,451000,454000};
__constant__ int c_CNTN[14]   = {40000,100000,3000,40000,20000,40000,20000,40000,8000,40000,60000,40000,3000,60000};
__constant__ int c_SRCOFF[14] = {0,100000,100000,140000,100000,143000,100000,143000,100000,163000,100000,171000,171000,231000};
__constant__ int c_NODEPRE[8] = {0,100000,140000,143000,163000,171000,231000,234000};
__constant__ float c_INVND[7] = {1.0f, 1.0f/6.0f, 1.0f, 0.5f, 1.0f, 0.5f, 1.0f};
// slot ranges feeding each dst node type (for update_k)
__constant__ int c_UPD_NS[7]      = {1,6,1,2,1,2,1};
__constant__ int c_UPD_BASE[7][6] = {
    {40000,0,0,0,0,0},
    {0,143000,203000,263000,311000,411000},
    {140000,0,0,0,0,0},
    {183000,243000,0,0,0,0},
    {303000,0,0,0,0,0},
    {351000,454000,0,0,0,0},
    {451000,0,0,0,0,0}};
// bucket tables: per-type dst shift and bucket-id base (prefix of ceil(CNTN/2^sh))
__constant__ int c_BSH[14]   = {9,10,6,10,10,11,10,11,10,11,11,11,6,11};
__constant__ int c_BBASE[15] = {0,79,177,224,264,284,304,324,344,352,372,402,422,469,499};

static __device__ __forceinline__ unsigned short f2bf(float f) {
    unsigned u = __float_as_uint(f);
    u = u + 0x7FFFu + ((u >> 16) & 1u);
    return (unsigned short)(u >> 16);
}
static __device__ __forceinline__ float bf2f(unsigned short s) {
    return __uint_as_float(((unsigned)s) << 16);
}
static __device__ __forceinline__ unsigned short f2h(float f) {
    _Float16 h = (_Float16)f;
    return __builtin_bit_cast(unsigned short, h);
}
static __device__ __forceinline__ float h2f(unsigned short s) {
    _Float16 h = __builtin_bit_cast(_Float16, s);
    return (float)h;
}

struct EdgeArgs { const int* ei[14]; };

// ---------------- CSR build: stable two-pass binning ----------------
// Record: (slot_local:11 | src_global:18), < 2^29.

__global__ __launch_bounds__(256) void hist_k(EdgeArgs a, int* __restrict__ blkHist) {
    __shared__ int h[NBUK];
    int t = threadIdx.x;
    for (int i = t; i < NBUK; i += 256) h[i] = 0;
    __syncthreads();
    const int per = (TOTE + NBLK - 1) / NBLK;
    int s = blockIdx.x * per;
    int eEnd = min(s + per, TOTE);
    for (int g = s + t; g < eEnd; g += 256) {
        int e = 0;
        while (g >= c_EPRE[e + 1]) e++;
        int k = g - c_EPRE[e];
        int dst = a.ei[e][c_ECNT[e] + k];
        atomicAdd(&h[c_BBASE[e] + (dst >> c_BSH[e])], 1);
    }
    __syncthreads();
    for (int i = t; i < NBUK; i += 256) blkHist[(size_t)i * NBLK + blockIdx.x] = h[i];
}

__global__ __launch_bounds__(256) void scan_blk_k(int* __restrict__ blkHist, int* __restrict__ bktCnt) {
    int b = blockIdx.x;
    int* p = blkHist + (size_t)b * NBLK;
    int t = threadIdx.x;
    int4 v = *(int4*)&p[t * 4];
    int s = v.x + v.y + v.z + v.w;
    int lane = t & 63, w = t >> 6;
    __shared__ int wt[4];
    int incl = s;
    #pragma unroll
    for (int d = 1; d < 64; d <<= 1) { int o = __shfl_up(incl, d); if (lane >= d) incl += o; }
    if (lane == 63) wt[w] = incl;
    __syncthreads();
    int wb = 0;
    for (int i = 0; i < w; i++) wb += wt[i];
    int excl = incl - s + wb;
    int4 o;
    o.x = excl; o.y = excl + v.x; o.z = excl + v.x + v.y; o.w = excl + v.x + v.y + v.z;
    *(int4*)&p[t * 4] = o;
    if (t == 255) bktCnt[b] = excl + s;
}

__global__ __launch_bounds__(512) void scans2_k(const int* __restrict__ bktCnt, int* __restrict__ bktEdgeBase) {
    int t = threadIdx.x;
    int v = (t < NBUK) ? bktCnt[t] : 0;
    int lane = t & 63, w = t >> 6;
    __shared__ int wt[8];
    int incl = v;
    #pragma unroll
    for (int d = 1; d < 64; d <<= 1) { int o = __shfl_up(incl, d); if (lane >= d) incl += o; }
    if (lane == 63) wt[w] = incl;
    __syncthreads();
    int wb = 0;
    for (int i = 0; i < w; i++) wb += wt[i];
    int excl = incl - v + wb;
    if (t < NBUK) bktEdgeBase[t] = excl;
    if (t == NBUK - 1) bktEdgeBase[NBUK] = excl + v;
}

__global__ __launch_bounds__(256) void scatter_k(EdgeArgs a, const int* __restrict__ blkHist,
        const int* __restrict__ bktEdgeBase, unsigned* __restrict__ pool) {
    __shared__ int cur[NBUK];
    int t = threadIdx.x;
    for (int i = t; i < NBUK; i += 256)
        cur[i] = bktEdgeBase[i] + blkHist[(size_t)i * NBLK + blockIdx.x];
    __syncthreads();
    const int per = (TOTE + NBLK - 1) / NBLK;
    int s = blockIdx.x * per;
    int eEnd = min(s + per, TOTE);
    for (int g = s + t; g < eEnd; g += 256) {
        int e = 0;
        while (g >= c_EPRE[e + 1]) e++;
        int k = g - c_EPRE[e];
        int src = a.ei[e][k];
        int dst = a.ei[e][c_ECNT[e] + k];
        int sh = c_BSH[e];
        unsigned rec = ((unsigned)(dst & ((1 << sh) - 1)) << 18) | (unsigned)(c_SRCOFF[e] + src);
        int p = atomicAdd(&cur[c_BBASE[e] + (dst >> sh)], 1);
        pool[p] = rec;
    }
}

__global__ __launch_bounds__(256) void csrfill_k(
        const unsigned* __restrict__ pool, const int* __restrict__ bktEdgeBase,
        int* __restrict__ cnt, int* __restrict__ cursor, float* __restrict__ invdeg,
        int* __restrict__ col) {
    __shared__ int hist[2048];
    __shared__ int cur[2048];
    __shared__ int wtot[4];
    __shared__ int wbase[4];
    int b = blockIdx.x;
    int t = threadIdx.x;
    int e = 0;
    while (b >= c_BBASE[e + 1]) e++;
    int lb = b - c_BBASE[e];
    int sh = c_BSH[e];
    int s0t = lb << sh;
    int span = min(1 << sh, c_CNTN[e] - s0t);
    int gs0 = c_CNTOFF[e] + s0t;
    int ebase = bktEdgeBase[b];
    int nrec = bktEdgeBase[b + 1] - ebase;

    for (int i = t; i < span; i += 256) hist[i] = 0;
    __syncthreads();
    for (int i = t; i < nrec; i += 256) atomicAdd(&hist[pool[ebase + i] >> 18], 1);
    __syncthreads();
    int base = t * 8, loc = 0, lv[8];
    #pragma unroll
    for (int i = 0; i < 8; i++) {
        int ii = base + i;
        int v = (ii < span) ? hist[ii] : 0;
        lv[i] = loc; loc += v;
    }
    int lane = t & 63, w = t >> 6;
    int incl = loc;
    #pragma unroll
    for (int d = 1; d < 64; d <<= 1) { int o = __shfl_up(incl, d); if (lane >= d) incl += o; }
    if (lane == 63) wtot[w] = incl;
    __syncthreads();
    if (t == 0) { int s2 = 0; for (int i = 0; i < 4; i++) { wbase[i] = s2; s2 += wtot[i]; } }
    __syncthreads();
    int texcl = incl - loc + wbase[w];
    #pragma unroll
    for (int i = 0; i < 8; i++) {
        int ii = base + i;
        if (ii < span) cur[ii] = texcl + lv[i];
    }
    __syncthreads();
    for (int i = t; i < span; i += 256) {
        int c = hist[i];
        cnt[gs0 + i] = c;
        cursor[gs0 + i] = ebase + cur[i] + c;     // end semantics
        invdeg[gs0 + i] = 1.0f / fmaxf((float)c, 1.0f);
    }
    __syncthreads();
    for (int i = t; i < nrec; i += 256) {
        unsigned rec = pool[ebase + i];
        int p = atomicAdd(&cur[rec >> 18], 1);
        col[ebase + p] = (int)(rec & 0x3FFFFu);
    }
}

// ---------------- conversions ----------------
struct XArgs { const float* x[7]; };
__global__ __launch_bounds__(256) void convx_k(XArgs a, unsigned short* __restrict__ hbf) {
    int i4 = blockIdx.x * 256 + threadIdx.x;
    if (i4 >= TOTN * 32) return;           // float4 index
    int idx = i4 * 4;
    int t = 0;
    while (idx >= c_NODEPRE[t + 1] * 128) t++;
    float4 v = *(const float4*)&a.x[t][idx - c_NODEPRE[t] * 128];
    uint2 p;
    p.x = (unsigned)f2bf(v.x) | ((unsigned)f2bf(v.y) << 16);
    p.y = (unsigned)f2bf(v.z) | ((unsigned)f2bf(v.w) << 16);
    *(uint2*)&hbf[idx] = p;
}

// weight slots: 0-6 Wp, 7-48 Wl(l*14+e), 49-90 Wr, 91 Wu, 92 Wv  (93 * 16384 elements)
struct WArgs { const float* Wp; const float* Wl; const float* Wr; const float* Wu; const float* Wv; };
__global__ __launch_bounds__(256) void convw_k(WArgs a, unsigned short* __restrict__ wbf) {
    int i4 = blockIdx.x * 256 + threadIdx.x;
    if (i4 >= 93 * 4096) return;
    int idx = i4 * 4;
    int m = idx >> 14;
    int i = idx & 16383;
    const float* src;
    if (m < 7)       src = a.Wp + (size_t)m * 16384;
    else if (m < 49) src = a.Wl + (size_t)(m - 7) * 16384;
    else if (m < 91) src = a.Wr + (size_t)(m - 49) * 16384;
    else if (m == 91) src = a.Wu;
    else              src = a.Wv;
    float4 v = *(const float4*)&src[i];
    uint2 p;
    p.x = (unsigned)f2bf(v.x) | ((unsigned)f2bf(v.y) << 16);
    p.y = (unsigned)f2bf(v.z) | ((unsigned)f2bf(v.w) << 16);
    *(uint2*)&wbf[idx] = p;
}

// ---------------- aggregation: one wave per slot, quarter-wave per neighbor ----------------
// float2v accumulators -> v_pk_add_f32 candidates; col-index loads rotated one
// iteration ahead to break the col->row dependent-load chain.
#define ACC8v(u) do { \
    v01 += (float2v){__uint_as_float((u).x << 16), __uint_as_float((u).x & 0xFFFF0000u)}; \
    v23 += (float2v){__uint_as_float((u).y << 16), __uint_as_float((u).y & 0xFFFF0000u)}; \
    v45 += (float2v){__uint_as_float((u).z << 16), __uint_as_float((u).z & 0xFFFF0000u)}; \
    v67 += (float2v){__uint_as_float((u).w << 16), __uint_as_float((u).w & 0xFFFF0000u)}; } while (0)

__global__ __launch_bounds__(256) void agg_k(
        const int* __restrict__ cnt, const int* __restrict__ cursor,
        const float* __restrict__ inv_deg, const int* __restrict__ col,
        const unsigned short* __restrict__ hbf, unsigned short* __restrict__ slotb) {
    int row = blockIdx.x * 4 + (threadIdx.x >> 6);
    if (row >= TOTC) return;
    int lane = threadIdx.x & 63;
    int q = lane >> 4, li = lane & 15;
    int nn = cnt[row];
    int rs = cursor[row] - nn;           // cursor==end
    const int* cp = col + rs;
    float2v v01 = {0.f, 0.f}, v23 = {0.f, 0.f}, v45 = {0.f, 0.f}, v67 = {0.f, 0.f};
    int j = 0;
    if (j + 8 <= nn) {
        int c0 = cp[q], c1 = cp[4 + q];
        for (; j + 8 <= nn; ) {
            int jn = j + 8;
            int n0 = 0, n1 = 0;
            if (jn + 8 <= nn) { n0 = cp[jn + q]; n1 = cp[jn + 4 + q]; }
            uint4 u0 = *(const uint4*)&hbf[(c0 << 7) + li * 8];
            uint4 u1 = *(const uint4*)&hbf[(c1 << 7) + li * 8];
            ACC8v(u0);
            ACC8v(u1);
            c0 = n0; c1 = n1; j = jn;
        }
    }
    for (; j < nn; j += 4) {
        if (j + q < nn) {
            int c = cp[j + q] << 7;
            uint4 u = *(const uint4*)&hbf[c + li * 8];
            ACC8v(u);
        }
    }
    float inv = inv_deg[row];
    float v[8] = {v01.x, v01.y, v23.x, v23.y, v45.x, v45.y, v67.x, v67.y};
    #pragma unroll
    for (int i = 0; i < 8; i++) {
        v[i] += __shfl_xor(v[i], 16);
        v[i] += __shfl_xor(v[i], 32);
        v[i] *= inv;
    }
    if (q == 0) {
        uint4 o;
        o.x = (unsigned)f2bf(v[0]) | ((unsigned)f2bf(v[1]) << 16);
        o.y = (unsigned)f2bf(v[2]) | ((unsigned)f2bf(v[3]) << 16);
        o.z = (unsigned)f2bf(v[4]) | ((unsigned)f2bf(v[5]) << 16);
        o.w = (unsigned)f2bf(v[6]) | ((unsigned)f2bf(v[7]) << 16);
        *(uint4*)&slotb[(size_t)row * HID + li * 8] = o;
    }
}

// ---------------- layer GEMM: out = l2norm(A1@W1^T + A2@W2^T + bias), f16 ----------------
// 128-row tile, both matmuls in one k-loop: 4x fewer barriers and 1.5x fewer staged
// loads per row than the 64-row two-pass version. Wave = 32 rows x 128 cols.
struct GemmLArgs {
    int blockPrefix[15];
    const unsigned short* W1[14];
    const unsigned short* W2[14];
    const float* bias[14];
    int cntoff[14];
    int dstoff[14];
    int rows[14];
};

__global__ __launch_bounds__(256) void gemm_l(GemmLArgs g,
        const unsigned short* __restrict__ hbf, unsigned short* __restrict__ slotb) {
    __shared__ short A1s[128 * 40];
    __shared__ short A2s[128 * 40];
    __shared__ short W1s[128 * 40];
    __shared__ short W2s[128 * 40];
    int b = blockIdx.x;
    int s = 0;
    while (b >= g.blockPrefix[s + 1]) s++;
    int rows = g.rows[s];
    int row0 = (b - g.blockPrefix[s]) * 128;
    int t = threadIdx.x;
    int wv = t >> 6, lane = t & 63;
    int q = lane >> 4, m15 = lane & 15;

    const uint4* A14 = (const uint4*)(slotb + (size_t)g.cntoff[s] * HID);
    const uint4* A24 = (const uint4*)(hbf + (size_t)g.dstoff[s] * HID);
    const uint4* W14 = (const uint4*)g.W1[s];
    const uint4* W24 = (const uint4*)g.W2[s];

    floatx4 acc[2][8];
    #pragma unroll
    for (int m = 0; m < 2; m++)
        #pragma unroll
        for (int bb = 0; bb < 8; bb++) acc[m][bb] = (floatx4){0.f, 0.f, 0.f, 0.f};

    for (int k0 = 0; k0 < 4; k0++) {       // 32-k chunk per step
        __syncthreads();
        #pragma unroll
        for (int i = 0; i < 2; i++) {
            int idx = t + i * 256;          // 0..511
            int row = idx >> 2, kc = idx & 3;
            uint4 va1 = make_uint4(0u, 0u, 0u, 0u), va2 = va1;
            if (row0 + row < rows) {
                va1 = A14[(size_t)(row0 + row) * 16 + k0 * 4 + kc];
                va2 = A24[(size_t)(row0 + row) * 16 + k0 * 4 + kc];
            }
            *(uint4*)&A1s[row * 40 + kc * 8] = va1;
            *(uint4*)&A2s[row * 40 + kc * 8] = va2;
            uint4 w1 = W14[(size_t)row * 16 + k0 * 4 + kc];   // row == W output-col here
            uint4 w2 = W24[(size_t)row * 16 + k0 * 4 + kc];
            *(uint4*)&W1s[row * 40 + kc * 8] = w1;
            *(uint4*)&W2s[row * 40 + kc * 8] = w2;
        }
        __syncthreads();
        bf16x8 a1[2], a2[2];
        #pragma unroll
        for (int m = 0; m < 2; m++) {
            int r = (wv * 32 + m * 16 + m15) * 40 + q * 8;
            a1[m] = __builtin_bit_cast(bf16x8, *(const short8*)&A1s[r]);
            a2[m] = __builtin_bit_cast(bf16x8, *(const short8*)&A2s[r]);
        }
        #pragma unroll
        for (int bb = 0; bb < 8; bb++) {
            int r = (bb * 16 + m15) * 40 + q * 8;
            bf16x8 w1 = __builtin_bit_cast(bf16x8, *(const short8*)&W1s[r]);
            bf16x8 w2 = __builtin_bit_cast(bf16x8, *(const short8*)&W2s[r]);
            #pragma unroll
            for (int m = 0; m < 2; m++) {
                acc[m][bb] = __builtin_amdgcn_mfma_f32_16x16x32_bf16(a1[m], w1, acc[m][bb], 0, 0, 0);
                acc[m][bb] = __builtin_amdgcn_mfma_f32_16x16x32_bf16(a2[m], w2, acc[m][bb], 0, 0, 0);
            }
        }
    }

    // epilogue: bias + per-row l2norm (reduce over bb + 16-lane group) + f16 store
    const float* bias = g.bias[s];
    #pragma unroll
    for (int bb = 0; bb < 8; bb++) {
        float bv = bias[bb * 16 + m15];
        #pragma unroll
        for (int m = 0; m < 2; m++)
            #pragma unroll
            for (int reg = 0; reg < 4; reg++) acc[m][bb][reg] += bv;
    }
    unsigned short* outp = slotb + (size_t)g.cntoff[s] * HID;
    #pragma unroll
    for (int m = 0; m < 2; m++) {
        #pragma unroll
        for (int reg = 0; reg < 4; reg++) {
            float ss = 0.f;
            #pragma unroll
            for (int bb = 0; bb < 8; bb++) ss += acc[m][bb][reg] * acc[m][bb][reg];
            ss += __shfl_xor(ss, 1);
            ss += __shfl_xor(ss, 2);
            ss += __shfl_xor(ss, 4);
            ss += __shfl_xor(ss, 8);
            float sc = 1.0f / fmaxf(sqrtf(ss), 1e-12f);
            int r = row0 + wv * 32 + m * 16 + q * 4 + reg;
            if (r < rows) {
                unsigned short* o = outp + (size_t)r * HID;
                #pragma unroll
                for (int bb = 0; bb < 8; bb++)
                    o[bb * 16 + m15] = f2h(acc[m][bb][reg] * sc);
            }
        }
    }
}

// ---------------- MFMA GEMM (input projection / heads) ----------------
struct GemmArgs {
    int blockPrefix[15];
    const unsigned short* A1[14];
    const unsigned short* W1[14];
    const float* bias[14]; void* out[14];
    int rows[14];
};

template<int MODE>
__global__ __launch_bounds__(256) void gemm_k(GemmArgs g) {
    __shared__ short As[64 * 40];
    __shared__ short Ws[128 * 40];
    int b = blockIdx.x;
    int s = 0;
    while (b >= g.blockPrefix[s + 1]) s++;
    int rows = g.rows[s];
    int row0 = (b - g.blockPrefix[s]) * 64;
    int t = threadIdx.x;
    int w = t >> 6, lane = t & 63;
    int q = lane >> 4, m15 = lane & 15;

    floatx4 acc[8];
    #pragma unroll
    for (int bb = 0; bb < 8; bb++) acc[bb] = (floatx4){0.f, 0.f, 0.f, 0.f};

    const uint4* A4 = (const uint4*)g.A1[s];
    const uint4* W4 = (const uint4*)g.W1[s];
    for (int k0 = 0; k0 < 128; k0 += 32) {
        __syncthreads();
        {   // A tile
            int row = t >> 2, kc = t & 3;
            uint4 v = make_uint4(0u, 0u, 0u, 0u);
            if (row0 + row < rows) v = A4[(size_t)(row0 + row) * 16 + (k0 >> 3) + kc];
            *(uint4*)&As[row * 40 + kc * 8] = v;
        }
        #pragma unroll
        for (int i = 0; i < 2; i++) {   // W tile
            int idx = t + i * 256;
            int c = idx >> 2, kc = idx & 3;
            uint4 v = W4[(size_t)c * 16 + (k0 >> 3) + kc];
            *(uint4*)&Ws[c * 40 + kc * 8] = v;
        }
        __syncthreads();
        bf16x8 af = __builtin_bit_cast(bf16x8, *(const short8*)&As[(w * 16 + m15) * 40 + q * 8]);
        #pragma unroll
        for (int bb = 0; bb < 8; bb++) {
            bf16x8 bf = __builtin_bit_cast(bf16x8, *(const short8*)&Ws[(bb * 16 + m15) * 40 + q * 8]);
            acc[bb] = __builtin_amdgcn_mfma_f32_16x16x32_bf16(af, bf, acc[bb], 0, 0, 0);
        }
    }

    const float* bias = g.bias[s];
    #pragma unroll
    for (int bb = 0; bb < 8; bb++) {
        float bv = bias[bb * 16 + m15];
        #pragma unroll
        for (int reg = 0; reg < 4; reg++) acc[bb][reg] += bv;
    }
    if (MODE != 0) {
        #pragma unroll
        for (int reg = 0; reg < 4; reg++) {
            float ss = 0.f;
            #pragma unroll
            for (int bb = 0; bb < 8; bb++) ss += acc[bb][reg] * acc[bb][reg];
            ss += __shfl_xor(ss, 1);
            ss += __shfl_xor(ss, 2);
            ss += __shfl_xor(ss, 4);
            ss += __shfl_xor(ss, 8);
            float sc = 1.0f / fmaxf(sqrtf(ss), 1e-12f);
            #pragma unroll
            for (int bb = 0; bb < 8; bb++) acc[bb][reg] *= sc;
        }
    }
    int rbase = row0 + w * 16 + q * 4;
    if (MODE == 3) {
        float* out = (float*)g.out[s];
        #pragma unroll
        for (int reg = 0; reg < 4; reg++) {
            int r = rbase + reg;
            if (r < rows) {
                float* o = out + (size_t)r * HID;
                #pragma unroll
                for (int bb = 0; bb < 8; bb++) o[bb * 16 + m15] = acc[bb][reg];
            }
        }
    } else {
        unsigned short* out = (unsigned short*)g.out[s];
        #pragma unroll
        for (int reg = 0; reg < 4; reg++) {
            int r = rbase + reg;
            if (r < rows) {
                unsigned short* o = out + (size_t)r * HID;
                #pragma unroll
                for (int bb = 0; bb < 8; bb++) o[bb * 16 + m15] = f2bf(acc[bb][reg]);
            }
        }
    }
}

// ---------------- per-layer update ----------------
__global__ __launch_bounds__(256) void update_k(unsigned short* __restrict__ hbf,
                                                const unsigned short* __restrict__ slotb,
                                                const float* __restrict__ ln_g, const float* __restrict__ ln_b, int l) {
    int row = blockIdx.x * 4 + (threadIdx.x >> 6);
    if (row >= TOTN) return;
    int lane = threadIdx.x & 63;
    int t = 0;
    while (row >= c_NODEPRE[t + 1]) t++;
    int r = row - c_NODEPRE[t];
    int ns = c_UPD_NS[t];
    float s0 = 0.f, s1 = 0.f;
    for (int s = 0; s < ns; s++) {
        const unsigned short* sp = slotb + (size_t)(c_UPD_BASE[t][s] + r) * HID;
        s0 += h2f(sp[lane]);
        s1 += h2f(sp[lane + 64]);
    }
    float invnd = c_INVND[t];
    const float* gg = ln_g + ((size_t)l * 7 + t) * HID;
    const float* bb = ln_b + ((size_t)l * 7 + t) * HID;
    unsigned short* hp = hbf + (size_t)row * HID;
    float x0 = s0 * invnd + bf2f(hp[lane]);
    float x1 = s1 * invnd + bf2f(hp[lane + 64]);
    float s = x0 + x1;
    s += __shfl_xor(s, 1);  s += __shfl_xor(s, 2);  s += __shfl_xor(s, 4);
    s += __shfl_xor(s, 8);  s += __shfl_xor(s, 16); s += __shfl_xor(s, 32);
    float mean = s * (1.0f / 128.0f);
    float d0 = x0 - mean, d1 = x1 - mean;
    float vs = d0 * d0 + d1 * d1;
    vs += __shfl_xor(vs, 1);  vs += __shfl_xor(vs, 2);  vs += __shfl_xor(vs, 4);
    vs += __shfl_xor(vs, 8);  vs += __shfl_xor(vs, 16); vs += __shfl_xor(vs, 32);
    float rstd = rsqrtf(vs * (1.0f / 128.0f) + 1e-5f);
    float y0 = d0 * rstd * gg[lane]      + bb[lane];
    float y1 = d1 * rstd * gg[lane + 64] + bb[lane + 64];
    hp[lane]      = f2bf(fmaxf(y0, 0.f));
    hp[lane + 64] = f2bf(fmaxf(y1, 0.f));
}

// ---------------- host ----------------
extern "C" void kernel_launch(void* const* d_in, const int* in_sizes, int n_in,
                              void* d_out, int out_size, void* d_ws, size_t ws_size,
                              hipStream_t stream) {
    (void)in_sizes; (void)n_in; (void)out_size; (void)ws_size;
    const float* Wp   = (const float*)d_in[21];
    const float* bp   = (const float*)d_in[22];
    const float* Wl   = (const float*)d_in[23];
    const float* bl   = (const float*)d_in[24];
    const float* Wr   = (const float*)d_in[25];
    const float* ln_g = (const float*)d_in[26];
    const float* ln_b = (const float*)d_in[27];
    const float* Wu   = (const float*)d_in[28];
    const float* bu   = (const float*)d_in[29];
    const float* Wv   = (const float*)d_in[30];
    const float* bv   = (const float*)d_in[31];
    float* out = (float*)d_out;

    // d_ws carve (~224.4 MB)
    unsigned short* h_bf   = (unsigned short*)d_ws;                  // TOTN*128 bf16
    unsigned short* w_bf   = h_bf + (size_t)TOTN * HID;              // 93*16384 bf16
    unsigned short* slotb  = w_bf + (size_t)93 * 16384;              // TOTC*128 bf16/f16
    int*            cnt    = (int*)(slotb + (size_t)TOTC * HID);     // TOTC
    int*            cursor = cnt + TOTC;                             // TOTC
    float*          invdeg = (float*)(cursor + TOTC);                // TOTC
    unsigned*       pool   = (unsigned*)(invdeg + TOTC);             // TOTE records
    int*            blkHist = (int*)(pool + (size_t)TOTE);           // NBUK*NBLK
    int*            ctrl    = blkHist + (size_t)NBUK * NBLK;         // control block
    int* bktCnt       = ctrl;                 // NBUK
    int* bktEdgeBase  = ctrl + NBUK;          // NBUK+1

    // d_out scratch (overwritten by final head GEMM)
    int* col = (int*)d_out;                                          // TOTE ints

    static const int CNTOFF[14] = {0,40000,140000,143000,183000,203000,243000,263000,303000,311000,351000,411000,451000,454000};
    static const int CNTN[14]   = {40000,100000,3000,40000,20000,40000,20000,40000,8000,40000,60000,40000,3000,60000};
    static const int DSTOFF[14] = {100000,0,140000,100000,143000,100000,143000,100000,163000,100000,171000,100000,231000,171000};
    static const int NODEPRE[8] = {0,100000,140000,143000,163000,171000,231000,234000};
    static const int NT[7]      = {100000,40000,3000,20000,8000,60000,3000};

    EdgeArgs ea;
    for (int e = 0; e < 14; e++) ea.ei[e] = (const int*)d_in[7 + e];

    // CSR build: histogram -> scans -> scatter -> per-bucket fill
    hist_k<<<NBLK, 256, 0, stream>>>(ea, blkHist);
    scan_blk_k<<<NBUK, 256, 0, stream>>>(blkHist, bktCnt);
    scans2_k<<<1, 512, 0, stream>>>(bktCnt, bktEdgeBase);
    scatter_k<<<NBLK, 256, 0, stream>>>(ea, blkHist, bktEdgeBase, pool);
    csrfill_k<<<NBUK, 256, 0, stream>>>(pool, bktEdgeBase, cnt, cursor, invdeg, col);

    {   // conversions
        XArgs xa;
        for (int t = 0; t < 7; t++) xa.x[t] = (const float*)d_in[t];
        convx_k<<<(TOTN * 32 + 255) / 256, 256, 0, stream>>>(xa, h_bf);
        WArgs wa = {Wp, Wl, Wr, Wu, Wv};
        convw_k<<<(93 * 4096 + 255) / 256, 256, 0, stream>>>(wa, w_bf);
    }

    // input projection (in-place bf16): h_bf[t] = x_bf[t] @ Wp[t]^T + bp[t]
    {
        GemmArgs ga;
        int pre = 0; ga.blockPrefix[0] = 0;
        for (int t = 0; t < 7; t++) {
            ga.A1[t] = h_bf + (size_t)NODEPRE[t] * HID;
            ga.W1[t] = w_bf + (size_t)t * 16384;
            ga.bias[t] = bp + (size_t)t * HID;
            ga.out[t] = h_bf + (size_t)NODEPRE[t] * HID;
            ga.rows[t] = NT[t];
            pre += (NT[t] + 63) / 64;
            ga.blockPrefix[t + 1] = pre;
        }
        for (int s = 7; s < 14; s++) { ga.blockPrefix[s + 1] = pre; ga.rows[s] = 0; }
        gemm_k<0><<<pre, 256, 0, stream>>>(ga);
    }

    // layers: agg + 128-row-tile gemm + update per layer
    int lgrid;
    GemmLArgs gl;
    {
        int pre = 0; gl.blockPrefix[0] = 0;
        for (int e = 0; e < 14; e++) {
            gl.rows[e]   = CNTN[e];
            gl.cntoff[e] = CNTOFF[e];
            gl.dstoff[e] = DSTOFF[e];
            pre += (CNTN[e] + 127) / 128;
            gl.blockPrefix[e + 1] = pre;
        }
        lgrid = pre;
    }
    for (int l = 0; l < 3; l++) {
        agg_k<<<(TOTC + 3) / 4, 256, 0, stream>>>(cnt, cursor, invdeg, col, h_bf, slotb);
        for (int e = 0; e < 14; e++) {
            gl.W1[e]   = w_bf + (size_t)(7  + l * 14 + e) * 16384;
            gl.W2[e]   = w_bf + (size_t)(49 + l * 14 + e) * 16384;
            gl.bias[e] = bl + ((size_t)l * 14 + e) * HID;
        }
        gemm_l<<<lgrid, 256, 0, stream>>>(gl, h_bf, slotb);
        update_k<<<(TOTN + 3) / 4, 256, 0, stream>>>(h_bf, slotb, ln_g, ln_b, l);
    }

    // heads: l2norm(h @ W^T + b) -> fp32 out (overwrites the col scratch in d_out)
    {
        GemmArgs ga;
        ga.blockPrefix[0] = 0;
        ga.A1[0] = h_bf;
        ga.W1[0] = w_bf + (size_t)91 * 16384;
        ga.bias[0] = bu;                        ga.out[0] = out;
        ga.rows[0] = 100000;
        ga.blockPrefix[1] = (100000 + 63) / 64;
        ga.A1[1] = h_bf + (size_t)100000 * HID;
        ga.W1[1] = w_bf + (size_t)92 * 16384;
        ga.bias[1] = bv;                        ga.out[1] = out + (size_t)100000 * HID;
        ga.rows[1] = 40000;
        int tot = ga.blockPrefix[1] + (40000 + 63) / 64;
        for (int s = 2; s < 14; s++) { ga.blockPrefix[s + 1] = tot; ga.rows[s] = 0; }
        ga.blockPrefix[2] = tot;
        gemm_k<3><<<tot, 256, 0, stream>>>(ga);
    }
}

// Round 7
// 1499.928 us; speedup vs baseline: 1.5356x; 1.0652x over previous
//
#include <hip/hip_runtime.h>
#include <math.h>

// ---------------- compile-time problem constants ----------------
#define TOTE 5400000   // total edges
#define TOTN 234000    // total node rows (all types concatenated)
#define TOTC 514000    // total dst slots over 14 edge types
#define HID  128

// bucketed CSR build (two-pass stable binning, no global atomics)
#define NBUK 499        // coarse dst-range buckets over all 14 edge types (span <= 2048 slots)
#define NBLK 1024       // blocks in hist_k / scatter_k (NBLK == 256*4 for scan_blk_k)

// ws carve (~224.4 MB, proven-safe ceiling 245.8 MB)
// d_out scratch: col (21.6MB), overwritten by the head GEMM at the end.

typedef __attribute__((ext_vector_type(8))) short short8;
typedef __attribute__((ext_vector_type(8))) __bf16 bf16x8;
typedef __attribute__((ext_vector_type(4))) float floatx4;
typedef __attribute__((ext_vector_type(2))) float float2v;

__constant__ int c_EPRE[15]   = {0,1000000,2000000,2500000,3000000,3200000,3400000,3600000,3800000,3900000,4000000,4300000,4600000,5000000,5400000};
__constant__ int c_ECNT[14]   = {1000000,1000000,500000,500000,200000,200000,200000,200000,100000,100000,300000,300000,400000,400000};
__constant__ int c_CNTOFF[14] = {0,40000,140000,143000,183000,203000,243000,263000,303000,311000,351000,411000,451000,454000};
__constant__ int c_CNTN[14]   = {40000,100000,3000,40000,20000,40000,20000,40000,8000,40000,60000,40000,3000,60000};
__constant__ int c_SRCOFF[14] = {0,100000,100000,140000,100000,143000,100000,143000,100000,163000,100000,171000,171000,231000};
__constant__ int c_NODEPRE[8] = {0,100000,140000,143000,163000,171000,231000,234000};
// bucket tables: per-type dst shift and bucket-id base (prefix of ceil(CNTN/2^sh))
__constant__ int c_BSH[14]   = {9,10,6,10,10,11,10,11,10,11,11,11,6,11};
__constant__ int c_BBASE[15] = {0,79,177,224,264,284,304,324,344,352,372,402,422,469,499};

static __device__ __forceinline__ unsigned short f2bf(float f) {
    unsigned u = __float_as_uint(f);
    u = u + 0x7FFFu + ((u >> 16) & 1u);
    return (unsigned short)(u >> 16);
}
static __device__ __forceinline__ float bf2f(unsigned short s) {
    return __uint_as_float(((unsigned)s) << 16);
}

struct EdgeArgs { const int* ei[14]; };

// ---------------- CSR build: stable two-pass binning ----------------
// Record: (slot_local:11 | src_global:18), < 2^29.

__global__ __launch_bounds__(256) void hist_k(EdgeArgs a, int* __restrict__ blkHist) {
    __shared__ int h[NBUK];
    int t = threadIdx.x;
    for (int i = t; i < NBUK; i += 256) h[i] = 0;
    __syncthreads();
    const int per = (TOTE + NBLK - 1) / NBLK;
    int s = blockIdx.x * per;
    int eEnd = min(s + per, TOTE);
    for (int g = s + t; g < eEnd; g += 256) {
        int e = 0;
        while (g >= c_EPRE[e + 1]) e++;
        int k = g - c_EPRE[e];
        int dst = a.ei[e][c_ECNT[e] + k];
        atomicAdd(&h[c_BBASE[e] + (dst >> c_BSH[e])], 1);
    }
    __syncthreads();
    for (int i = t; i < NBUK; i += 256) blkHist[(size_t)i * NBLK + blockIdx.x] = h[i];
}

__global__ __launch_bounds__(256) void scan_blk_k(int* __restrict__ blkHist, int* __restrict__ bktCnt) {
    int b = blockIdx.x;
    int* p = blkHist + (size_t)b * NBLK;
    int t = threadIdx.x;
    int4 v = *(int4*)&p[t * 4];
    int s = v.x + v.y + v.z + v.w;
    int lane = t & 63, w = t >> 6;
    __shared__ int wt[4];
    int incl = s;
    #pragma unroll
    for (int d = 1; d < 64; d <<= 1) { int o = __shfl_up(incl, d); if (lane >= d) incl += o; }
    if (lane == 63) wt[w] = incl;
    __syncthreads();
    int wb = 0;
    for (int i = 0; i < w; i++) wb += wt[i];
    int excl = incl - s + wb;
    int4 o;
    o.x = excl; o.y = excl + v.x; o.z = excl + v.x + v.y; o.w = excl + v.x + v.y + v.z;
    *(int4*)&p[t * 4] = o;
    if (t == 255) bktCnt[b] = excl + s;
}

__global__ __launch_bounds__(512) void scans2_k(const int* __restrict__ bktCnt, int* __restrict__ bktEdgeBase) {
    int t = threadIdx.x;
    int v = (t < NBUK) ? bktCnt[t] : 0;
    int lane = t & 63, w = t >> 6;
    __shared__ int wt[8];
    int incl = v;
    #pragma unroll
    for (int d = 1; d < 64; d <<= 1) { int o = __shfl_up(incl, d); if (lane >= d) incl += o; }
    if (lane == 63) wt[w] = incl;
    __syncthreads();
    int wb = 0;
    for (int i = 0; i < w; i++) wb += wt[i];
    int excl = incl - v + wb;
    if (t < NBUK) bktEdgeBase[t] = excl;
    if (t == NBUK - 1) bktEdgeBase[NBUK] = excl + v;
}

__global__ __launch_bounds__(256) void scatter_k(EdgeArgs a, const int* __restrict__ blkHist,
        const int* __restrict__ bktEdgeBase, unsigned* __restrict__ pool) {
    __shared__ int cur[NBUK];
    int t = threadIdx.x;
    for (int i = t; i < NBUK; i += 256)
        cur[i] = bktEdgeBase[i] + blkHist[(size_t)i * NBLK + blockIdx.x];
    __syncthreads();
    const int per = (TOTE + NBLK - 1) / NBLK;
    int s = blockIdx.x * per;
    int eEnd = min(s + per, TOTE);
    for (int g = s + t; g < eEnd; g += 256) {
        int e = 0;
        while (g >= c_EPRE[e + 1]) e++;
        int k = g - c_EPRE[e];
        int src = a.ei[e][k];
        int dst = a.ei[e][c_ECNT[e] + k];
        int sh = c_BSH[e];
        unsigned rec = ((unsigned)(dst & ((1 << sh) - 1)) << 18) | (unsigned)(c_SRCOFF[e] + src);
        int p = atomicAdd(&cur[c_BBASE[e] + (dst >> sh)], 1);
        pool[p] = rec;
    }
}

__global__ __launch_bounds__(256) void csrfill_k(
        const unsigned* __restrict__ pool, const int* __restrict__ bktEdgeBase,
        int* __restrict__ cnt, int* __restrict__ cursor, float* __restrict__ invdeg,
        int* __restrict__ col) {
    __shared__ int hist[2048];
    __shared__ int cur[2048];
    __shared__ int wtot[4];
    __shared__ int wbase[4];
    int b = blockIdx.x;
    int t = threadIdx.x;
    int e = 0;
    while (b >= c_BBASE[e + 1]) e++;
    int lb = b - c_BBASE[e];
    int sh = c_BSH[e];
    int s0t = lb << sh;
    int span = min(1 << sh, c_CNTN[e] - s0t);
    int gs0 = c_CNTOFF[e] + s0t;
    int ebase = bktEdgeBase[b];
    int nrec = bktEdgeBase[b + 1] - ebase;

    for (int i = t; i < span; i += 256) hist[i] = 0;
    __syncthreads();
    for (int i = t; i < nrec; i += 256) atomicAdd(&hist[pool[ebase + i] >> 18], 1);
    __syncthreads();
    int base = t * 8, loc = 0, lv[8];
    #pragma unroll
    for (int i = 0; i < 8; i++) {
        int ii = base + i;
        int v = (ii < span) ? hist[ii] : 0;
        lv[i] = loc; loc += v;
    }
    int lane = t & 63, w = t >> 6;
    int incl = loc;
    #pragma unroll
    for (int d = 1; d < 64; d <<= 1) { int o = __shfl_up(incl, d); if (lane >= d) incl += o; }
    if (lane == 63) wtot[w] = incl;
    __syncthreads();
    if (t == 0) { int s2 = 0; for (int i = 0; i < 4; i++) { wbase[i] = s2; s2 += wtot[i]; } }
    __syncthreads();
    int texcl = incl - loc + wbase[w];
    #pragma unroll
    for (int i = 0; i < 8; i++) {
        int ii = base + i;
        if (ii < span) cur[ii] = texcl + lv[i];
    }
    __syncthreads();
    for (int i = t; i < span; i += 256) {
        int c = hist[i];
        cnt[gs0 + i] = c;
        cursor[gs0 + i] = ebase + cur[i] + c;     // end semantics
        invdeg[gs0 + i] = 1.0f / fmaxf((float)c, 1.0f);
    }
    __syncthreads();
    for (int i = t; i < nrec; i += 256) {
        unsigned rec = pool[ebase + i];
        int p = atomicAdd(&cur[rec >> 18], 1);
        col[ebase + p] = (int)(rec & 0x3FFFFu);
    }
}

// ---------------- conversions ----------------
struct XArgs { const float* x[7]; };
__global__ __launch_bounds__(256) void convx_k(XArgs a, unsigned short* __restrict__ hbf) {
    int i4 = blockIdx.x * 256 + threadIdx.x;
    if (i4 >= TOTN * 32) return;           // float4 index
    int idx = i4 * 4;
    int t = 0;
    while (idx >= c_NODEPRE[t + 1] * 128) t++;
    float4 v = *(const float4*)&a.x[t][idx - c_NODEPRE[t] * 128];
    uint2 p;
    p.x = (unsigned)f2bf(v.x) | ((unsigned)f2bf(v.y) << 16);
    p.y = (unsigned)f2bf(v.z) | ((unsigned)f2bf(v.w) << 16);
    *(uint2*)&hbf[idx] = p;
}

// weight slots: 0-6 Wp, 7-48 Wl(l*14+e), 49-90 Wr, 91 Wu, 92 Wv  (93 * 16384 elements)
struct WArgs { const float* Wp; const float* Wl; const float* Wr; const float* Wu; const float* Wv; };
__global__ __launch_bounds__(256) void convw_k(WArgs a, unsigned short* __restrict__ wbf) {
    int i4 = blockIdx.x * 256 + threadIdx.x;
    if (i4 >= 93 * 4096) return;
    int idx = i4 * 4;
    int m = idx >> 14;
    int i = idx & 16383;
    const float* src;
    if (m < 7)       src = a.Wp + (size_t)m * 16384;
    else if (m < 49) src = a.Wl + (size_t)(m - 7) * 16384;
    else if (m < 91) src = a.Wr + (size_t)(m - 49) * 16384;
    else if (m == 91) src = a.Wu;
    else              src = a.Wv;
    float4 v = *(const float4*)&src[i];
    uint2 p;
    p.x = (unsigned)f2bf(v.x) | ((unsigned)f2bf(v.y) << 16);
    p.y = (unsigned)f2bf(v.z) | ((unsigned)f2bf(v.w) << 16);
    *(uint2*)&wbf[idx] = p;
}

// ---------------- aggregation: one wave per slot, quarter-wave per neighbor ----------------
#define ACC8v(u) do { \
    v01 += (float2v){__uint_as_float((u).x << 16), __uint_as_float((u).x & 0xFFFF0000u)}; \
    v23 += (float2v){__uint_as_float((u).y << 16), __uint_as_float((u).y & 0xFFFF0000u)}; \
    v45 += (float2v){__uint_as_float((u).z << 16), __uint_as_float((u).z & 0xFFFF0000u)}; \
    v67 += (float2v){__uint_as_float((u).w << 16), __uint_as_float((u).w & 0xFFFF0000u)}; } while (0)

__global__ __launch_bounds__(256) void agg_k(
        const int* __restrict__ cnt, const int* __restrict__ cursor,
        const float* __restrict__ inv_deg, const int* __restrict__ col,
        const unsigned short* __restrict__ hbf, unsigned short* __restrict__ slotb) {
    int row = blockIdx.x * 4 + (threadIdx.x >> 6);
    if (row >= TOTC) return;
    int lane = threadIdx.x & 63;
    int q = lane >> 4, li = lane & 15;
    int nn = cnt[row];
    int rs = cursor[row] - nn;           // cursor==end
    const int* cp = col + rs;
    float2v v01 = {0.f, 0.f}, v23 = {0.f, 0.f}, v45 = {0.f, 0.f}, v67 = {0.f, 0.f};
    int j = 0;
    if (j + 8 <= nn) {
        int c0 = cp[q], c1 = cp[4 + q];
        for (; j + 8 <= nn; ) {
            int jn = j + 8;
            int n0 = 0, n1 = 0;
            if (jn + 8 <= nn) { n0 = cp[jn + q]; n1 = cp[jn + 4 + q]; }
            uint4 u0 = *(const uint4*)&hbf[(c0 << 7) + li * 8];
            uint4 u1 = *(const uint4*)&hbf[(c1 << 7) + li * 8];
            ACC8v(u0);
            ACC8v(u1);
            c0 = n0; c1 = n1; j = jn;
        }
    }
    for (; j < nn; j += 4) {
        if (j + q < nn) {
            int c = cp[j + q] << 7;
            uint4 u = *(const uint4*)&hbf[c + li * 8];
            ACC8v(u);
        }
    }
    float inv = inv_deg[row];
    float v[8] = {v01.x, v01.y, v23.x, v23.y, v45.x, v45.y, v67.x, v67.y};
    #pragma unroll
    for (int i = 0; i < 8; i++) {
        v[i] += __shfl_xor(v[i], 16);
        v[i] += __shfl_xor(v[i], 32);
        v[i] *= inv;
    }
    if (q == 0) {
        uint4 o;
        o.x = (unsigned)f2bf(v[0]) | ((unsigned)f2bf(v[1]) << 16);
        o.y = (unsigned)f2bf(v[2]) | ((unsigned)f2bf(v[3]) << 16);
        o.z = (unsigned)f2bf(v[4]) | ((unsigned)f2bf(v[5]) << 16);
        o.w = (unsigned)f2bf(v[6]) | ((unsigned)f2bf(v[7]) << 16);
        *(uint4*)&slotb[(size_t)row * HID + li * 8] = o;
    }
}

// ---------------- fused per-node-type layer: GEMMs + l2norm-sum + LN + relu ----------------
// Block = 64 rows of ONE node type. Persistent LDS tile As2 holds the 64 h-rows
// (MFMA A2 operand AND the residual). For each feeding edge type: 64-row k-loop GEMM
// (A1 = agg slots from slotb, A2 from As2, W staged per 32-k chunk), bias, per-row
// l2norm in-register, accumulate into accsum. Final: /NUM_DST + residual -> LN -> relu
// -> write h. Eliminates the slotb f16 round-trip and update_k entirely.
struct FusArgs {
    int blockPrefix[8];
    int ns[7];
    int a1off[7][6];                   // slot-range base per feeding edge type
    const unsigned short* W1[7][6];    // Wl
    const unsigned short* W2[7][6];    // Wr
    const float* bias[7][6];
    int nodepre[7];
    int nrows[7];
    float invnd[7];
};

__global__ __launch_bounds__(256) void fusedln_k(FusArgs g,
        unsigned short* __restrict__ hbf, const unsigned short* __restrict__ slotb,
        const float* __restrict__ ln_g, const float* __restrict__ ln_b, int l) {
    __shared__ short As2[64 * 168];    // persistent h tile: row*168 + chunk*40 + elem
    __shared__ short A1c[64 * 40];     // per-k-chunk A1 tile
    __shared__ short W1c[128 * 40];
    __shared__ short W2c[128 * 40];
    int b = blockIdx.x;
    int t = 0;
    while (b >= g.blockPrefix[t + 1]) t++;
    int nrows = g.nrows[t];
    int row0 = (b - g.blockPrefix[t]) * 64;
    int dst0 = g.nodepre[t] + row0;
    int tid = threadIdx.x;
    int w = tid >> 6, lane = tid & 63;
    int q = lane >> 4, m15 = lane & 15;

    // stage the 64 h rows (zero-fill tail)
    {
        const uint4* h4 = (const uint4*)hbf;
        #pragma unroll
        for (int it = 0; it < 4; it++) {
            int c = tid + it * 256;            // 0..1023: row(6b) x kc16(4b)
            int row = c >> 4, kc = c & 15;
            uint4 v = make_uint4(0u, 0u, 0u, 0u);
            if (row0 + row < nrows) v = h4[(size_t)(dst0 + row) * 16 + kc];
            *(uint4*)&As2[row * 168 + (kc >> 2) * 40 + (kc & 3) * 8] = v;
        }
    }

    floatx4 accsum[8];
    #pragma unroll
    for (int bb = 0; bb < 8; bb++) accsum[bb] = (floatx4){0.f, 0.f, 0.f, 0.f};

    int ns = g.ns[t];
    for (int ei = 0; ei < ns; ei++) {
        const uint4* A14 = (const uint4*)(slotb + (size_t)g.a1off[t][ei] * HID);
        const uint4* W14 = (const uint4*)g.W1[t][ei];
        const uint4* W24 = (const uint4*)g.W2[t][ei];
        floatx4 acc[8];
        #pragma unroll
        for (int bb = 0; bb < 8; bb++) acc[bb] = (floatx4){0.f, 0.f, 0.f, 0.f};
        for (int k0 = 0; k0 < 4; k0++) {
            __syncthreads();
            {   // A1 chunk: 64 rows x 32 k
                int row = tid >> 2, kc = tid & 3;
                uint4 v = make_uint4(0u, 0u, 0u, 0u);
                if (row0 + row < nrows) v = A14[(size_t)(row0 + row) * 16 + k0 * 4 + kc];
                *(uint4*)&A1c[row * 40 + kc * 8] = v;
            }
            #pragma unroll
            for (int i = 0; i < 2; i++) {   // W chunks: 128 cols x 32 k each
                int idx = tid + i * 256;
                int c = idx >> 2, kc = idx & 3;
                *(uint4*)&W1c[c * 40 + kc * 8] = W14[(size_t)c * 16 + k0 * 4 + kc];
                *(uint4*)&W2c[c * 40 + kc * 8] = W24[(size_t)c * 16 + k0 * 4 + kc];
            }
            __syncthreads();
            bf16x8 a1 = __builtin_bit_cast(bf16x8, *(const short8*)&A1c[(w * 16 + m15) * 40 + q * 8]);
            bf16x8 a2 = __builtin_bit_cast(bf16x8, *(const short8*)&As2[(w * 16 + m15) * 168 + k0 * 40 + q * 8]);
            #pragma unroll
            for (int bb = 0; bb < 8; bb++) {
                bf16x8 w1 = __builtin_bit_cast(bf16x8, *(const short8*)&W1c[(bb * 16 + m15) * 40 + q * 8]);
                bf16x8 w2 = __builtin_bit_cast(bf16x8, *(const short8*)&W2c[(bb * 16 + m15) * 40 + q * 8]);
                acc[bb] = __builtin_amdgcn_mfma_f32_16x16x32_bf16(a1, w1, acc[bb], 0, 0, 0);
                acc[bb] = __builtin_amdgcn_mfma_f32_16x16x32_bf16(a2, w2, acc[bb], 0, 0, 0);
            }
        }
        // edge-type epilogue: bias + per-row l2norm, accumulate
        const float* bias = g.bias[t][ei];
        #pragma unroll
        for (int bb = 0; bb < 8; bb++) {
            float bv = bias[bb * 16 + m15];
            #pragma unroll
            for (int reg = 0; reg < 4; reg++) acc[bb][reg] += bv;
        }
        #pragma unroll
        for (int reg = 0; reg < 4; reg++) {
            float ss = 0.f;
            #pragma unroll
            for (int bb = 0; bb < 8; bb++) ss += acc[bb][reg] * acc[bb][reg];
            ss += __shfl_xor(ss, 1);
            ss += __shfl_xor(ss, 2);
            ss += __shfl_xor(ss, 4);
            ss += __shfl_xor(ss, 8);
            float sc = 1.0f / fmaxf(sqrtf(ss), 1e-12f);
            #pragma unroll
            for (int bb = 0; bb < 8; bb++) accsum[bb][reg] += acc[bb][reg] * sc;
        }
    }

    // final: x = accsum*invnd + residual; LayerNorm; relu; write h
    float invnd = g.invnd[t];
    const float* gg = ln_g + ((size_t)l * 7 + t) * HID;
    const float* bbp = ln_b + ((size_t)l * 7 + t) * HID;
    float gv[8], bv2[8];
    #pragma unroll
    for (int bb = 0; bb < 8; bb++) {
        gv[bb]  = gg[bb * 16 + m15];
        bv2[bb] = bbp[bb * 16 + m15];
    }
    #pragma unroll
    for (int reg = 0; reg < 4; reg++) {
        int lrow = w * 16 + q * 4 + reg;          // C-layout row
        float x[8];
        #pragma unroll
        for (int bb = 0; bb < 8; bb++) {
            float resid = bf2f((unsigned short)As2[lrow * 168 + (bb >> 1) * 40 + (bb & 1) * 16 + m15]);
            x[bb] = accsum[bb][reg] * invnd + resid;
        }
        float s = 0.f;
        #pragma unroll
        for (int bb = 0; bb < 8; bb++) s += x[bb];
        s += __shfl_xor(s, 1);
        s += __shfl_xor(s, 2);
        s += __shfl_xor(s, 4);
        s += __shfl_xor(s, 8);
        float mean = s * (1.0f / 128.0f);
        float vs = 0.f;
        #pragma unroll
        for (int bb = 0; bb < 8; bb++) { float d = x[bb] - mean; vs += d * d; }
        vs += __shfl_xor(vs, 1);
        vs += __shfl_xor(vs, 2);
        vs += __shfl_xor(vs, 4);
        vs += __shfl_xor(vs, 8);
        float rstd = rsqrtf(vs * (1.0f / 128.0f) + 1e-5f);
        if (row0 + lrow < nrows) {
            unsigned short* o = hbf + (size_t)(dst0 + lrow) * HID;
            #pragma unroll
            for (int bb = 0; bb < 8; bb++) {
                float y = (x[bb] - mean) * rstd * gv[bb] + bv2[bb];
                o[bb * 16 + m15] = f2bf(fmaxf(y, 0.f));
            }
        }
    }
}

// ---------------- MFMA GEMM (input projection / heads) ----------------
struct GemmArgs {
    int blockPrefix[15];
    const unsigned short* A1[14];
    const unsigned short* W1[14];
    const float* bias[14]; void* out[14];
    int rows[14];
};

template<int MODE>
__global__ __launch_bounds__(256) void gemm_k(GemmArgs g) {
    __shared__ short As[64 * 40];
    __shared__ short Ws[128 * 40];
    int b = blockIdx.x;
    int s = 0;
    while (b >= g.blockPrefix[s + 1]) s++;
    int rows = g.rows[s];
    int row0 = (b - g.blockPrefix[s]) * 64;
    int t = threadIdx.x;
    int w = t >> 6, lane = t & 63;
    int q = lane >> 4, m15 = lane & 15;

    floatx4 acc[8];
    #pragma unroll
    for (int bb = 0; bb < 8; bb++) acc[bb] = (floatx4){0.f, 0.f, 0.f, 0.f};

    const uint4* A4 = (const uint4*)g.A1[s];
    const uint4* W4 = (const uint4*)g.W1[s];
    for (int k0 = 0; k0 < 128; k0 += 32) {
        __syncthreads();
        {   // A tile
            int row = t >> 2, kc = t & 3;
            uint4 v = make_uint4(0u, 0u, 0u, 0u);
            if (row0 + row < rows) v = A4[(size_t)(row0 + row) * 16 + (k0 >> 3) + kc];
            *(uint4*)&As[row * 40 + kc * 8] = v;
        }
        #pragma unroll
        for (int i = 0; i < 2; i++) {   // W tile
            int idx = t + i * 256;
            int c = idx >> 2, kc = idx & 3;
            uint4 v = W4[(size_t)c * 16 + (k0 >> 3) + kc];
            *(uint4*)&Ws[c * 40 + kc * 8] = v;
        }
        __syncthreads();
        bf16x8 af = __builtin_bit_cast(bf16x8, *(const short8*)&As[(w * 16 + m15) * 40 + q * 8]);
        #pragma unroll
        for (int bb = 0; bb < 8; bb++) {
            bf16x8 bf = __builtin_bit_cast(bf16x8, *(const short8*)&Ws[(bb * 16 + m15) * 40 + q * 8]);
            acc[bb] = __builtin_amdgcn_mfma_f32_16x16x32_bf16(af, bf, acc[bb], 0, 0, 0);
        }
    }

    const float* bias = g.bias[s];
    #pragma unroll
    for (int bb = 0; bb < 8; bb++) {
        float bv = bias[bb * 16 + m15];
        #pragma unroll
        for (int reg = 0; reg < 4; reg++) acc[bb][reg] += bv;
    }
    if (MODE != 0) {
        #pragma unroll
        for (int reg = 0; reg < 4; reg++) {
            float ss = 0.f;
            #pragma unroll
            for (int bb = 0; bb < 8; bb++) ss += acc[bb][reg] * acc[bb][reg];
            ss += __shfl_xor(ss, 1);
            ss += __shfl_xor(ss, 2);
            ss += __shfl_xor(ss, 4);
            ss += __shfl_xor(ss, 8);
            float sc = 1.0f / fmaxf(sqrtf(ss), 1e-12f);
            #pragma unroll
            for (int bb = 0; bb < 8; bb++) acc[bb][reg] *= sc;
        }
    }
    int rbase = row0 + w * 16 + q * 4;
    if (MODE == 3) {
        float* out = (float*)g.out[s];
        #pragma unroll
        for (int reg = 0; reg < 4; reg++) {
            int r = rbase + reg;
            if (r < rows) {
                float* o = out + (size_t)r * HID;
                #pragma unroll
                for (int bb = 0; bb < 8; bb++) o[bb * 16 + m15] = acc[bb][reg];
            }
        }
    } else {
        unsigned short* out = (unsigned short*)g.out[s];
        #pragma unroll
        for (int reg = 0; reg < 4; reg++) {
            int r = rbase + reg;
            if (r < rows) {
                unsigned short* o = out + (size_t)r * HID;
                #pragma unroll
                for (int bb = 0; bb < 8; bb++) o[bb * 16 + m15] = f2bf(acc[bb][reg]);
            }
        }
    }
}

// ---------------- host ----------------
extern "C" void kernel_launch(void* const* d_in, const int* in_sizes, int n_in,
                              void* d_out, int out_size, void* d_ws, size_t ws_size,
                              hipStream_t stream) {
    (void)in_sizes; (void)n_in; (void)out_size; (void)ws_size;
    const float* Wp   = (const float*)d_in[21];
    const float* bp   = (const float*)d_in[22];
    const float* bl   = (const float*)d_in[24];
    const float* ln_g = (const float*)d_in[26];
    const float* ln_b = (const float*)d_in[27];
    const float* bu   = (const float*)d_in[29];
    const float* bv   = (const float*)d_in[31];
    float* out = (float*)d_out;

    // d_ws carve (~224.4 MB)
    unsigned short* h_bf   = (unsigned short*)d_ws;                  // TOTN*128 bf16
    unsigned short* w_bf   = h_bf + (size_t)TOTN * HID;              // 93*16384 bf16
    unsigned short* slotb  = w_bf + (size_t)93 * 16384;              // TOTC*128 bf16
    int*            cnt    = (int*)(slotb + (size_t)TOTC * HID);     // TOTC
    int*            cursor = cnt + TOTC;                             // TOTC
    float*          invdeg = (float*)(cursor + TOTC);                // TOTC
    unsigned*       pool   = (unsigned*)(invdeg + TOTC);             // TOTE records
    int*            blkHist = (int*)(pool + (size_t)TOTE);           // NBUK*NBLK
    int*            ctrl    = blkHist + (size_t)NBUK * NBLK;         // control block
    int* bktCnt       = ctrl;                 // NBUK
    int* bktEdgeBase  = ctrl + NBUK;          // NBUK+1

    // d_out scratch (overwritten by final head GEMM)
    int* col = (int*)d_out;                                          // TOTE ints

    static const int CNTOFF[14] = {0,40000,140000,143000,183000,203000,243000,263000,303000,311000,351000,411000,451000,454000};
    static const int NODEPRE[8] = {0,100000,140000,143000,163000,171000,231000,234000};
    static const int NT[7]      = {100000,40000,3000,20000,8000,60000,3000};
    static const int FEED_NS[7] = {1,6,1,2,1,2,1};
    static const int FEED_E[7][6] = {
        {1,0,0,0,0,0},
        {0,3,5,7,9,11},
        {2,0,0,0,0,0},
        {4,6,0,0,0,0},
        {8,0,0,0,0,0},
        {10,13,0,0,0,0},
        {12,0,0,0,0,0}};
    static const float INVND[7] = {1.0f, 1.0f/6.0f, 1.0f, 0.5f, 1.0f, 0.5f, 1.0f};

    EdgeArgs ea;
    for (int e = 0; e < 14; e++) ea.ei[e] = (const int*)d_in[7 + e];

    // CSR build: histogram -> scans -> scatter -> per-bucket fill
    hist_k<<<NBLK, 256, 0, stream>>>(ea, blkHist);
    scan_blk_k<<<NBUK, 256, 0, stream>>>(blkHist, bktCnt);
    scans2_k<<<1, 512, 0, stream>>>(bktCnt, bktEdgeBase);
    scatter_k<<<NBLK, 256, 0, stream>>>(ea, blkHist, bktEdgeBase, pool);
    csrfill_k<<<NBUK, 256, 0, stream>>>(pool, bktEdgeBase, cnt, cursor, invdeg, col);

    {   // conversions
        XArgs xa;
        for (int t = 0; t < 7; t++) xa.x[t] = (const float*)d_in[t];
        convx_k<<<(TOTN * 32 + 255) / 256, 256, 0, stream>>>(xa, h_bf);
        WArgs wa = {Wp, (const float*)d_in[23], (const float*)d_in[25],
                    (const float*)d_in[28], (const float*)d_in[30]};
        convw_k<<<(93 * 4096 + 255) / 256, 256, 0, stream>>>(wa, w_bf);
    }

    // input projection (in-place bf16): h_bf[t] = x_bf[t] @ Wp[t]^T + bp[t]
    {
        GemmArgs ga;
        int pre = 0; ga.blockPrefix[0] = 0;
        for (int t = 0; t < 7; t++) {
            ga.A1[t] = h_bf + (size_t)NODEPRE[t] * HID;
            ga.W1[t] = w_bf + (size_t)t * 16384;
            ga.bias[t] = bp + (size_t)t * HID;
            ga.out[t] = h_bf + (size_t)NODEPRE[t] * HID;
            ga.rows[t] = NT[t];
            pre += (NT[t] + 63) / 64;
            ga.blockPrefix[t + 1] = pre;
        }
        for (int s = 7; s < 14; s++) { ga.blockPrefix[s + 1] = pre; ga.rows[s] = 0; }
        gemm_k<0><<<pre, 256, 0, stream>>>(ga);
    }

    // layers: agg + fused(GEMMs+LN) per layer
    FusArgs fa;
    int fgrid;
    {
        int pre = 0; fa.blockPrefix[0] = 0;
        for (int t = 0; t < 7; t++) {
            fa.ns[t] = FEED_NS[t];
            fa.nodepre[t] = NODEPRE[t];
            fa.nrows[t] = NT[t];
            fa.invnd[t] = INVND[t];
            for (int j = 0; j < 6; j++) fa.a1off[t][j] = CNTOFF[FEED_E[t][j]];
            pre += (NT[t] + 63) / 64;
            fa.blockPrefix[t + 1] = pre;
        }
        fgrid = pre;
    }
    for (int l = 0; l < 3; l++) {
        agg_k<<<(TOTC + 3) / 4, 256, 0, stream>>>(cnt, cursor, invdeg, col, h_bf, slotb);
        for (int t = 0; t < 7; t++) {
            for (int j = 0; j < 6; j++) {
                int e = FEED_E[t][j];
                fa.W1[t][j]   = w_bf + (size_t)(7  + l * 14 + e) * 16384;
                fa.W2[t][j]   = w_bf + (size_t)(49 + l * 14 + e) * 16384;
                fa.bias[t][j] = bl + ((size_t)l * 14 + e) * HID;
            }
        }
        fusedln_k<<<fgrid, 256, 0, stream>>>(fa, h_bf, slotb, ln_g, ln_b, l);
    }

    // heads: l2norm(h @ W^T + b) -> fp32 out (overwrites the col scratch in d_out)
    {
        GemmArgs ga;
        ga.blockPrefix[0] = 0;
        ga.A1[0] = h_bf;
        ga.W1[0] = w_bf + (size_t)91 * 16384;
        ga.bias[0] = bu;                        ga.out[0] = out;
        ga.rows[0] = 100000;
        ga.blockPrefix[1] = (100000 + 63) / 64;
        ga.A1[1] = h_bf + (size_t)100000 * HID;
        ga.W1[1] = w_bf + (size_t)92 * 16384;
        ga.bias[1] = bv;                        ga.out[1] = out + (size_t)100000 * HID;
        ga.rows[1] = 40000;
        int tot = ga.blockPrefix[1] + (40000 + 63) / 64;
        for (int s = 2; s < 14; s++) { ga.blockPrefix[s + 1] = tot; ga.rows[s] = 0; }
        ga.blockPrefix[2] = tot;
        gemm_k<3><<<tot, 256, 0, stream>>>(ga);
    }
}

// Round 8
// 1345.463 us; speedup vs baseline: 1.7119x; 1.1148x over previous
//
#include <hip/hip_runtime.h>
#include <math.h>

// ---------------- compile-time problem constants ----------------
#define TOTE 5400000   // total edges
#define TOTN 234000    // total node rows (all types concatenated)
#define TOTC 514000    // total dst slots over 14 edge types
#define HID  128

// bucketed CSR build (two-pass stable binning, no global atomics)
#define NBUK 499        // coarse dst-range buckets over all 14 edge types (span <= 2048 slots)
#define NBLK 1024       // blocks in hist_k / scatter_k (NBLK == 256*4 for scan_blk_k)

// ws carve (~224.4 MB, proven-safe ceiling 245.8 MB)
// d_out scratch: col (21.6MB), overwritten by the head GEMM at the end.

typedef __attribute__((ext_vector_type(8))) short short8;
typedef __attribute__((ext_vector_type(8))) __bf16 bf16x8;
typedef __attribute__((ext_vector_type(4))) float floatx4;
typedef __attribute__((ext_vector_type(2))) float float2v;

__constant__ int c_EPRE[15]   = {0,1000000,2000000,2500000,3000000,3200000,3400000,3600000,3800000,3900000,4000000,4300000,4600000,5000000,5400000};
__constant__ int c_ECNT[14]   = {1000000,1000000,500000,500000,200000,200000,200000,200000,100000,100000,300000,300000,400000,400000};
__constant__ int c_CNTOFF[14] = {0,40000,140000,143000,183000,203000,243000,263000,303000,311000,351000,411000,451000,454000};
__constant__ int c_CNTN[14]   = {40000,100000,3000,40000,20000,40000,20000,40000,8000,40000,60000,40000,3000,60000};
__constant__ int c_SRCOFF[14] = {0,100000,100000,140000,100000,143000,100000,143000,100000,163000,100000,171000,171000,231000};
__constant__ int c_NODEPRE[8] = {0,100000,140000,143000,163000,171000,231000,234000};
// bucket tables: per-type dst shift and bucket-id base (prefix of ceil(CNTN/2^sh))
__constant__ int c_BSH[14]   = {9,10,6,10,10,11,10,11,10,11,11,11,6,11};
__constant__ int c_BBASE[15] = {0,79,177,224,264,284,304,324,344,352,372,402,422,469,499};

static __device__ __forceinline__ unsigned short f2bf(float f) {
    unsigned u = __float_as_uint(f);
    u = u + 0x7FFFu + ((u >> 16) & 1u);
    return (unsigned short)(u >> 16);
}
static __device__ __forceinline__ float bf2f(unsigned short s) {
    return __uint_as_float(((unsigned)s) << 16);
}

struct EdgeArgs { const int* ei[14]; };

// ---------------- CSR build: stable two-pass binning ----------------
// Record: (slot_local:11 | src_global:18), < 2^29.

__global__ __launch_bounds__(256) void hist_k(EdgeArgs a, int* __restrict__ blkHist) {
    __shared__ int h[NBUK];
    int t = threadIdx.x;
    for (int i = t; i < NBUK; i += 256) h[i] = 0;
    __syncthreads();
    const int per = (TOTE + NBLK - 1) / NBLK;
    int s = blockIdx.x * per;
    int eEnd = min(s + per, TOTE);
    for (int g = s + t; g < eEnd; g += 256) {
        int e = 0;
        while (g >= c_EPRE[e + 1]) e++;
        int k = g - c_EPRE[e];
        int dst = a.ei[e][c_ECNT[e] + k];
        atomicAdd(&h[c_BBASE[e] + (dst >> c_BSH[e])], 1);
    }
    __syncthreads();
    for (int i = t; i < NBUK; i += 256) blkHist[(size_t)i * NBLK + blockIdx.x] = h[i];
}

__global__ __launch_bounds__(256) void scan_blk_k(int* __restrict__ blkHist, int* __restrict__ bktCnt) {
    int b = blockIdx.x;
    int* p = blkHist + (size_t)b * NBLK;
    int t = threadIdx.x;
    int4 v = *(int4*)&p[t * 4];
    int s = v.x + v.y + v.z + v.w;
    int lane = t & 63, w = t >> 6;
    __shared__ int wt[4];
    int incl = s;
    #pragma unroll
    for (int d = 1; d < 64; d <<= 1) { int o = __shfl_up(incl, d); if (lane >= d) incl += o; }
    if (lane == 63) wt[w] = incl;
    __syncthreads();
    int wb = 0;
    for (int i = 0; i < w; i++) wb += wt[i];
    int excl = incl - s + wb;
    int4 o;
    o.x = excl; o.y = excl + v.x; o.z = excl + v.x + v.y; o.w = excl + v.x + v.y + v.z;
    *(int4*)&p[t * 4] = o;
    if (t == 255) bktCnt[b] = excl + s;
}

__global__ __launch_bounds__(512) void scans2_k(const int* __restrict__ bktCnt, int* __restrict__ bktEdgeBase) {
    int t = threadIdx.x;
    int v = (t < NBUK) ? bktCnt[t] : 0;
    int lane = t & 63, w = t >> 6;
    __shared__ int wt[8];
    int incl = v;
    #pragma unroll
    for (int d = 1; d < 64; d <<= 1) { int o = __shfl_up(incl, d); if (lane >= d) incl += o; }
    if (lane == 63) wt[w] = incl;
    __syncthreads();
    int wb = 0;
    for (int i = 0; i < w; i++) wb += wt[i];
    int excl = incl - v + wb;
    if (t < NBUK) bktEdgeBase[t] = excl;
    if (t == NBUK - 1) bktEdgeBase[NBUK] = excl + v;
}

__global__ __launch_bounds__(256) void scatter_k(EdgeArgs a, const int* __restrict__ blkHist,
        const int* __restrict__ bktEdgeBase, unsigned* __restrict__ pool) {
    __shared__ int cur[NBUK];
    int t = threadIdx.x;
    for (int i = t; i < NBUK; i += 256)
        cur[i] = bktEdgeBase[i] + blkHist[(size_t)i * NBLK + blockIdx.x];
    __syncthreads();
    const int per = (TOTE + NBLK - 1) / NBLK;
    int s = blockIdx.x * per;
    int eEnd = min(s + per, TOTE);
    for (int g = s + t; g < eEnd; g += 256) {
        int e = 0;
        while (g >= c_EPRE[e + 1]) e++;
        int k = g - c_EPRE[e];
        int src = a.ei[e][k];
        int dst = a.ei[e][c_ECNT[e] + k];
        int sh = c_BSH[e];
        unsigned rec = ((unsigned)(dst & ((1 << sh) - 1)) << 18) | (unsigned)(c_SRCOFF[e] + src);
        int p = atomicAdd(&cur[c_BBASE[e] + (dst >> sh)], 1);
        pool[p] = rec;
    }
}

__global__ __launch_bounds__(256) void csrfill_k(
        const unsigned* __restrict__ pool, const int* __restrict__ bktEdgeBase,
        int* __restrict__ cnt, int* __restrict__ cursor, float* __restrict__ invdeg,
        int* __restrict__ col) {
    __shared__ int hist[2048];
    __shared__ int cur[2048];
    __shared__ int wtot[4];
    __shared__ int wbase[4];
    int b = blockIdx.x;
    int t = threadIdx.x;
    int e = 0;
    while (b >= c_BBASE[e + 1]) e++;
    int lb = b - c_BBASE[e];
    int sh = c_BSH[e];
    int s0t = lb << sh;
    int span = min(1 << sh, c_CNTN[e] - s0t);
    int gs0 = c_CNTOFF[e] + s0t;
    int ebase = bktEdgeBase[b];
    int nrec = bktEdgeBase[b + 1] - ebase;

    for (int i = t; i < span; i += 256) hist[i] = 0;
    __syncthreads();
    for (int i = t; i < nrec; i += 256) atomicAdd(&hist[pool[ebase + i] >> 18], 1);
    __syncthreads();
    int base = t * 8, loc = 0, lv[8];
    #pragma unroll
    for (int i = 0; i < 8; i++) {
        int ii = base + i;
        int v = (ii < span) ? hist[ii] : 0;
        lv[i] = loc; loc += v;
    }
    int lane = t & 63, w = t >> 6;
    int incl = loc;
    #pragma unroll
    for (int d = 1; d < 64; d <<= 1) { int o = __shfl_up(incl, d); if (lane >= d) incl += o; }
    if (lane == 63) wtot[w] = incl;
    __syncthreads();
    if (t == 0) { int s2 = 0; for (int i = 0; i < 4; i++) { wbase[i] = s2; s2 += wtot[i]; } }
    __syncthreads();
    int texcl = incl - loc + wbase[w];
    #pragma unroll
    for (int i = 0; i < 8; i++) {
        int ii = base + i;
        if (ii < span) cur[ii] = texcl + lv[i];
    }
    __syncthreads();
    for (int i = t; i < span; i += 256) {
        int c = hist[i];
        cnt[gs0 + i] = c;
        cursor[gs0 + i] = ebase + cur[i] + c;     // end semantics
        invdeg[gs0 + i] = 1.0f / fmaxf((float)c, 1.0f);
    }
    __syncthreads();
    for (int i = t; i < nrec; i += 256) {
        unsigned rec = pool[ebase + i];
        int p = atomicAdd(&cur[rec >> 18], 1);
        col[ebase + p] = (int)(rec & 0x3FFFFu);
    }
}

// ---------------- conversions ----------------
struct XArgs { const float* x[7]; };
__global__ __launch_bounds__(256) void convx_k(XArgs a, unsigned short* __restrict__ hbf) {
    int i4 = blockIdx.x * 256 + threadIdx.x;
    if (i4 >= TOTN * 32) return;           // float4 index
    int idx = i4 * 4;
    int t = 0;
    while (idx >= c_NODEPRE[t + 1] * 128) t++;
    float4 v = *(const float4*)&a.x[t][idx - c_NODEPRE[t] * 128];
    uint2 p;
    p.x = (unsigned)f2bf(v.x) | ((unsigned)f2bf(v.y) << 16);
    p.y = (unsigned)f2bf(v.z) | ((unsigned)f2bf(v.w) << 16);
    *(uint2*)&hbf[idx] = p;
}

// weight slots: 0-6 Wp, 7-48 Wl(l*14+e), 49-90 Wr, 91 Wu, 92 Wv  (93 * 16384 elements)
struct WArgs { const float* Wp; const float* Wl; const float* Wr; const float* Wu; const float* Wv; };
__global__ __launch_bounds__(256) void convw_k(WArgs a, unsigned short* __restrict__ wbf) {
    int i4 = blockIdx.x * 256 + threadIdx.x;
    if (i4 >= 93 * 4096) return;
    int idx = i4 * 4;
    int m = idx >> 14;
    int i = idx & 16383;
    const float* src;
    if (m < 7)       src = a.Wp + (size_t)m * 16384;
    else if (m < 49) src = a.Wl + (size_t)(m - 7) * 16384;
    else if (m < 91) src = a.Wr + (size_t)(m - 49) * 16384;
    else if (m == 91) src = a.Wu;
    else              src = a.Wv;
    float4 v = *(const float4*)&src[i];
    uint2 p;
    p.x = (unsigned)f2bf(v.x) | ((unsigned)f2bf(v.y) << 16);
    p.y = (unsigned)f2bf(v.z) | ((unsigned)f2bf(v.w) << 16);
    *(uint2*)&wbf[idx] = p;
}

// ---------------- aggregation: one QUARTER-WAVE per slot ----------------
// Each 16-lane quarter owns one slot; lane li covers elems [li*8, li*8+8).
// Neighbors walked sequentially, unrolled x4 with all 4 row-loads issued before
// accumulation: 4 quarters x 4 rows = 4KB in flight per wave (8x the wave-per-slot
// scheme) for the latency-bound random gather. No cross-lane reduce needed.
#define ACC8v(u) do { \
    v01 += (float2v){__uint_as_float((u).x << 16), __uint_as_float((u).x & 0xFFFF0000u)}; \
    v23 += (float2v){__uint_as_float((u).y << 16), __uint_as_float((u).y & 0xFFFF0000u)}; \
    v45 += (float2v){__uint_as_float((u).z << 16), __uint_as_float((u).z & 0xFFFF0000u)}; \
    v67 += (float2v){__uint_as_float((u).w << 16), __uint_as_float((u).w & 0xFFFF0000u)}; } while (0)

__global__ __launch_bounds__(256) void agg_k(
        const int* __restrict__ cnt, const int* __restrict__ cursor,
        const float* __restrict__ inv_deg, const int* __restrict__ col,
        const unsigned short* __restrict__ hbf, unsigned short* __restrict__ slotb) {
    int row = blockIdx.x * 16 + (threadIdx.x >> 4);
    if (row >= TOTC) return;
    int li = threadIdx.x & 15;
    int nn = cnt[row];
    int rs = cursor[row] - nn;           // cursor==end
    const int* cp = col + rs;
    float2v v01 = {0.f, 0.f}, v23 = {0.f, 0.f}, v45 = {0.f, 0.f}, v67 = {0.f, 0.f};
    int j = 0;
    for (; j + 4 <= nn; j += 4) {
        int c0 = cp[j]     << 7;
        int c1 = cp[j + 1] << 7;
        int c2 = cp[j + 2] << 7;
        int c3 = cp[j + 3] << 7;
        uint4 u0 = *(const uint4*)&hbf[c0 + li * 8];
        uint4 u1 = *(const uint4*)&hbf[c1 + li * 8];
        uint4 u2 = *(const uint4*)&hbf[c2 + li * 8];
        uint4 u3 = *(const uint4*)&hbf[c3 + li * 8];
        ACC8v(u0);
        ACC8v(u1);
        ACC8v(u2);
        ACC8v(u3);
    }
    for (; j < nn; j++) {
        int c = cp[j] << 7;
        uint4 u = *(const uint4*)&hbf[c + li * 8];
        ACC8v(u);
    }
    float inv = inv_deg[row];
    float v[8] = {v01.x, v01.y, v23.x, v23.y, v45.x, v45.y, v67.x, v67.y};
    uint4 o;
    o.x = (unsigned)f2bf(v[0] * inv) | ((unsigned)f2bf(v[1] * inv) << 16);
    o.y = (unsigned)f2bf(v[2] * inv) | ((unsigned)f2bf(v[3] * inv) << 16);
    o.z = (unsigned)f2bf(v[4] * inv) | ((unsigned)f2bf(v[5] * inv) << 16);
    o.w = (unsigned)f2bf(v[6] * inv) | ((unsigned)f2bf(v[7] * inv) << 16);
    *(uint4*)&slotb[(size_t)row * HID + li * 8] = o;
}

// ---------------- fused per-node-type layer: GEMMs + l2norm-sum + LN + relu ----------------
struct FusArgs {
    int blockPrefix[8];
    int ns[7];
    int a1off[7][6];                   // slot-range base per feeding edge type
    const unsigned short* W1[7][6];    // Wl
    const unsigned short* W2[7][6];    // Wr
    const float* bias[7][6];
    int nodepre[7];
    int nrows[7];
    float invnd[7];
};

__global__ __launch_bounds__(256) void fusedln_k(FusArgs g,
        unsigned short* __restrict__ hbf, const unsigned short* __restrict__ slotb,
        const float* __restrict__ ln_g, const float* __restrict__ ln_b, int l) {
    __shared__ short As2[64 * 168];    // persistent h tile: row*168 + chunk*40 + elem
    __shared__ short A1c[64 * 40];     // per-k-chunk A1 tile
    __shared__ short W1c[128 * 40];
    __shared__ short W2c[128 * 40];
    int b = blockIdx.x;
    int t = 0;
    while (b >= g.blockPrefix[t + 1]) t++;
    int nrows = g.nrows[t];
    int row0 = (b - g.blockPrefix[t]) * 64;
    int dst0 = g.nodepre[t] + row0;
    int tid = threadIdx.x;
    int w = tid >> 6, lane = tid & 63;
    int q = lane >> 4, m15 = lane & 15;

    // stage the 64 h rows (zero-fill tail)
    {
        const uint4* h4 = (const uint4*)hbf;
        #pragma unroll
        for (int it = 0; it < 4; it++) {
            int c = tid + it * 256;            // 0..1023: row(6b) x kc16(4b)
            int row = c >> 4, kc = c & 15;
            uint4 v = make_uint4(0u, 0u, 0u, 0u);
            if (row0 + row < nrows) v = h4[(size_t)(dst0 + row) * 16 + kc];
            *(uint4*)&As2[row * 168 + (kc >> 2) * 40 + (kc & 3) * 8] = v;
        }
    }

    floatx4 accsum[8];
    #pragma unroll
    for (int bb = 0; bb < 8; bb++) accsum[bb] = (floatx4){0.f, 0.f, 0.f, 0.f};

    int ns = g.ns[t];
    for (int ei = 0; ei < ns; ei++) {
        const uint4* A14 = (const uint4*)(slotb + (size_t)g.a1off[t][ei] * HID);
        const uint4* W14 = (const uint4*)g.W1[t][ei];
        const uint4* W24 = (const uint4*)g.W2[t][ei];
        floatx4 acc[8];
        #pragma unroll
        for (int bb = 0; bb < 8; bb++) acc[bb] = (floatx4){0.f, 0.f, 0.f, 0.f};
        for (int k0 = 0; k0 < 4; k0++) {
            __syncthreads();
            {   // A1 chunk: 64 rows x 32 k
                int row = tid >> 2, kc = tid & 3;
                uint4 v = make_uint4(0u, 0u, 0u, 0u);
                if (row0 + row < nrows) v = A14[(size_t)(row0 + row) * 16 + k0 * 4 + kc];
                *(uint4*)&A1c[row * 40 + kc * 8] = v;
            }
            #pragma unroll
            for (int i = 0; i < 2; i++) {   // W chunks: 128 cols x 32 k each
                int idx = tid + i * 256;
                int c = idx >> 2, kc = idx & 3;
                *(uint4*)&W1c[c * 40 + kc * 8] = W14[(size_t)c * 16 + k0 * 4 + kc];
                *(uint4*)&W2c[c * 40 + kc * 8] = W24[(size_t)c * 16 + k0 * 4 + kc];
            }
            __syncthreads();
            bf16x8 a1 = __builtin_bit_cast(bf16x8, *(const short8*)&A1c[(w * 16 + m15) * 40 + q * 8]);
            bf16x8 a2 = __builtin_bit_cast(bf16x8, *(const short8*)&As2[(w * 16 + m15) * 168 + k0 * 40 + q * 8]);
            #pragma unroll
            for (int bb = 0; bb < 8; bb++) {
                bf16x8 w1 = __builtin_bit_cast(bf16x8, *(const short8*)&W1c[(bb * 16 + m15) * 40 + q * 8]);
                bf16x8 w2 = __builtin_bit_cast(bf16x8, *(const short8*)&W2c[(bb * 16 + m15) * 40 + q * 8]);
                acc[bb] = __builtin_amdgcn_mfma_f32_16x16x32_bf16(a1, w1, acc[bb], 0, 0, 0);
                acc[bb] = __builtin_amdgcn_mfma_f32_16x16x32_bf16(a2, w2, acc[bb], 0, 0, 0);
            }
        }
        // edge-type epilogue: bias + per-row l2norm, accumulate
        const float* bias = g.bias[t][ei];
        #pragma unroll
        for (int bb = 0; bb < 8; bb++) {
            float bv = bias[bb * 16 + m15];
            #pragma unroll
            for (int reg = 0; reg < 4; reg++) acc[bb][reg] += bv;
        }
        #pragma unroll
        for (int reg = 0; reg < 4; reg++) {
            float ss = 0.f;
            #pragma unroll
            for (int bb = 0; bb < 8; bb++) ss += acc[bb][reg] * acc[bb][reg];
            ss += __shfl_xor(ss, 1);
            ss += __shfl_xor(ss, 2);
            ss += __shfl_xor(ss, 4);
            ss += __shfl_xor(ss, 8);
            float sc = 1.0f / fmaxf(sqrtf(ss), 1e-12f);
            #pragma unroll
            for (int bb = 0; bb < 8; bb++) accsum[bb][reg] += acc[bb][reg] * sc;
        }
    }

    // final: x = accsum*invnd + residual; LayerNorm; relu; write h
    float invnd = g.invnd[t];
    const float* gg = ln_g + ((size_t)l * 7 + t) * HID;
    const float* bbp = ln_b + ((size_t)l * 7 + t) * HID;
    float gv[8], bv2[8];
    #pragma unroll
    for (int bb = 0; bb < 8; bb++) {
        gv[bb]  = gg[bb * 16 + m15];
        bv2[bb] = bbp[bb * 16 + m15];
    }
    #pragma unroll
    for (int reg = 0; reg < 4; reg++) {
        int lrow = w * 16 + q * 4 + reg;          // C-layout row
        float x[8];
        #pragma unroll
        for (int bb = 0; bb < 8; bb++) {
            float resid = bf2f((unsigned short)As2[lrow * 168 + (bb >> 1) * 40 + (bb & 1) * 16 + m15]);
            x[bb] = accsum[bb][reg] * invnd + resid;
        }
        float s = 0.f;
        #pragma unroll
        for (int bb = 0; bb < 8; bb++) s += x[bb];
        s += __shfl_xor(s, 1);
        s += __shfl_xor(s, 2);
        s += __shfl_xor(s, 4);
        s += __shfl_xor(s, 8);
        float mean = s * (1.0f / 128.0f);
        float vs = 0.f;
        #pragma unroll
        for (int bb = 0; bb < 8; bb++) { float d = x[bb] - mean; vs += d * d; }
        vs += __shfl_xor(vs, 1);
        vs += __shfl_xor(vs, 2);
        vs += __shfl_xor(vs, 4);
        vs += __shfl_xor(vs, 8);
        float rstd = rsqrtf(vs * (1.0f / 128.0f) + 1e-5f);
        if (row0 + lrow < nrows) {
            unsigned short* o = hbf + (size_t)(dst0 + lrow) * HID;
            #pragma unroll
            for (int bb = 0; bb < 8; bb++) {
                float y = (x[bb] - mean) * rstd * gv[bb] + bv2[bb];
                o[bb * 16 + m15] = f2bf(fmaxf(y, 0.f));
            }
        }
    }
}

// ---------------- MFMA GEMM (input projection / heads) ----------------
struct GemmArgs {
    int blockPrefix[15];
    const unsigned short* A1[14];
    const unsigned short* W1[14];
    const float* bias[14]; void* out[14];
    int rows[14];
};

template<int MODE>
__global__ __launch_bounds__(256) void gemm_k(GemmArgs g) {
    __shared__ short As[64 * 40];
    __shared__ short Ws[128 * 40];
    int b = blockIdx.x;
    int s = 0;
    while (b >= g.blockPrefix[s + 1]) s++;
    int rows = g.rows[s];
    int row0 = (b - g.blockPrefix[s]) * 64;
    int t = threadIdx.x;
    int w = t >> 6, lane = t & 63;
    int q = lane >> 4, m15 = lane & 15;

    floatx4 acc[8];
    #pragma unroll
    for (int bb = 0; bb < 8; bb++) acc[bb] = (floatx4){0.f, 0.f, 0.f, 0.f};

    const uint4* A4 = (const uint4*)g.A1[s];
    const uint4* W4 = (const uint4*)g.W1[s];
    for (int k0 = 0; k0 < 128; k0 += 32) {
        __syncthreads();
        {   // A tile
            int row = t >> 2, kc = t & 3;
            uint4 v = make_uint4(0u, 0u, 0u, 0u);
            if (row0 + row < rows) v = A4[(size_t)(row0 + row) * 16 + (k0 >> 3) + kc];
            *(uint4*)&As[row * 40 + kc * 8] = v;
        }
        #pragma unroll
        for (int i = 0; i < 2; i++) {   // W tile
            int idx = t + i * 256;
            int c = idx >> 2, kc = idx & 3;
            uint4 v = W4[(size_t)c * 16 + (k0 >> 3) + kc];
            *(uint4*)&Ws[c * 40 + kc * 8] = v;
        }
        __syncthreads();
        bf16x8 af = __builtin_bit_cast(bf16x8, *(const short8*)&As[(w * 16 + m15) * 40 + q * 8]);
        #pragma unroll
        for (int bb = 0; bb < 8; bb++) {
            bf16x8 bf = __builtin_bit_cast(bf16x8, *(const short8*)&Ws[(bb * 16 + m15) * 40 + q * 8]);
            acc[bb] = __builtin_amdgcn_mfma_f32_16x16x32_bf16(af, bf, acc[bb], 0, 0, 0);
        }
    }

    const float* bias = g.bias[s];
    #pragma unroll
    for (int bb = 0; bb < 8; bb++) {
        float bv = bias[bb * 16 + m15];
        #pragma unroll
        for (int reg = 0; reg < 4; reg++) acc[bb][reg] += bv;
    }
    if (MODE != 0) {
        #pragma unroll
        for (int reg = 0; reg < 4; reg++) {
            float ss = 0.f;
            #pragma unroll
            for (int bb = 0; bb < 8; bb++) ss += acc[bb][reg] * acc[bb][reg];
            ss += __shfl_xor(ss, 1);
            ss += __shfl_xor(ss, 2);
            ss += __shfl_xor(ss, 4);
            ss += __shfl_xor(ss, 8);
            float sc = 1.0f / fmaxf(sqrtf(ss), 1e-12f);
            #pragma unroll
            for (int bb = 0; bb < 8; bb++) acc[bb][reg] *= sc;
        }
    }
    int rbase = row0 + w * 16 + q * 4;
    if (MODE == 3) {
        float* out = (float*)g.out[s];
        #pragma unroll
        for (int reg = 0; reg < 4; reg++) {
            int r = rbase + reg;
            if (r < rows) {
                float* o = out + (size_t)r * HID;
                #pragma unroll
                for (int bb = 0; bb < 8; bb++) o[bb * 16 + m15] = acc[bb][reg];
            }
        }
    } else {
        unsigned short* out = (unsigned short*)g.out[s];
        #pragma unroll
        for (int reg = 0; reg < 4; reg++) {
            int r = rbase + reg;
            if (r < rows) {
                unsigned short* o = out + (size_t)r * HID;
                #pragma unroll
                for (int bb = 0; bb < 8; bb++) o[bb * 16 + m15] = f2bf(acc[bb][reg]);
            }
        }
    }
}

// ---------------- host ----------------
extern "C" void kernel_launch(void* const* d_in, const int* in_sizes, int n_in,
                              void* d_out, int out_size, void* d_ws, size_t ws_size,
                              hipStream_t stream) {
    (void)in_sizes; (void)n_in; (void)out_size; (void)ws_size;
    const float* Wp   = (const float*)d_in[21];
    const float* bp   = (const float*)d_in[22];
    const float* bl   = (const float*)d_in[24];
    const float* ln_g = (const float*)d_in[26];
    const float* ln_b = (const float*)d_in[27];
    const float* bu   = (const float*)d_in[29];
    const float* bv   = (const float*)d_in[31];
    float* out = (float*)d_out;

    // d_ws carve (~224.4 MB)
    unsigned short* h_bf   = (unsigned short*)d_ws;                  // TOTN*128 bf16
    unsigned short* w_bf   = h_bf + (size_t)TOTN * HID;              // 93*16384 bf16
    unsigned short* slotb  = w_bf + (size_t)93 * 16384;              // TOTC*128 bf16
    int*            cnt    = (int*)(slotb + (size_t)TOTC * HID);     // TOTC
    int*            cursor = cnt + TOTC;                             // TOTC
    float*          invdeg = (float*)(cursor + TOTC);                // TOTC
    unsigned*       pool   = (unsigned*)(invdeg + TOTC);             // TOTE records
    int*            blkHist = (int*)(pool + (size_t)TOTE);           // NBUK*NBLK
    int*            ctrl    = blkHist + (size_t)NBUK * NBLK;         // control block
    int* bktCnt       = ctrl;                 // NBUK
    int* bktEdgeBase  = ctrl + NBUK;          // NBUK+1

    // d_out scratch (overwritten by final head GEMM)
    int* col = (int*)d_out;                                          // TOTE ints

    static const int CNTOFF[14] = {0,40000,140000,143000,183000,203000,243000,263000,303000,311000,351000,411000,451000,454000};
    static const int NODEPRE[8] = {0,100000,140000,143000,163000,171000,231000,234000};
    static const int NT[7]      = {100000,40000,3000,20000,8000,60000,3000};
    static const int FEED_NS[7] = {1,6,1,2,1,2,1};
    static const int FEED_E[7][6] = {
        {1,0,0,0,0,0},
        {0,3,5,7,9,11},
        {2,0,0,0,0,0},
        {4,6,0,0,0,0},
        {8,0,0,0,0,0},
        {10,13,0,0,0,0},
        {12,0,0,0,0,0}};
    static const float INVND[7] = {1.0f, 1.0f/6.0f, 1.0f, 0.5f, 1.0f, 0.5f, 1.0f};

    EdgeArgs ea;
    for (int e = 0; e < 14; e++) ea.ei[e] = (const int*)d_in[7 + e];

    // CSR build: histogram -> scans -> scatter -> per-bucket fill
    hist_k<<<NBLK, 256, 0, stream>>>(ea, blkHist);
    scan_blk_k<<<NBUK, 256, 0, stream>>>(blkHist, bktCnt);
    scans2_k<<<1, 512, 0, stream>>>(bktCnt, bktEdgeBase);
    scatter_k<<<NBLK, 256, 0, stream>>>(ea, blkHist, bktEdgeBase, pool);
    csrfill_k<<<NBUK, 256, 0, stream>>>(pool, bktEdgeBase, cnt, cursor, invdeg, col);

    {   // conversions
        XArgs xa;
        for (int t = 0; t < 7; t++) xa.x[t] = (const float*)d_in[t];
        convx_k<<<(TOTN * 32 + 255) / 256, 256, 0, stream>>>(xa, h_bf);
        WArgs wa = {Wp, (const float*)d_in[23], (const float*)d_in[25],
                    (const float*)d_in[28], (const float*)d_in[30]};
        convw_k<<<(93 * 4096 + 255) / 256, 256, 0, stream>>>(wa, w_bf);
    }

    // input projection (in-place bf16): h_bf[t] = x_bf[t] @ Wp[t]^T + bp[t]
    {
        GemmArgs ga;
        int pre = 0; ga.blockPrefix[0] = 0;
        for (int t = 0; t < 7; t++) {
            ga.A1[t] = h_bf + (size_t)NODEPRE[t] * HID;
            ga.W1[t] = w_bf + (size_t)t * 16384;
            ga.bias[t] = bp + (size_t)t * HID;
            ga.out[t] = h_bf + (size_t)NODEPRE[t] * HID;
            ga.rows[t] = NT[t];
            pre += (NT[t] + 63) / 64;
            ga.blockPrefix[t + 1] = pre;
        }
        for (int s = 7; s < 14; s++) { ga.blockPrefix[s + 1] = pre; ga.rows[s] = 0; }
        gemm_k<0><<<pre, 256, 0, stream>>>(ga);
    }

    // layers: agg + fused(GEMMs+LN) per layer
    FusArgs fa;
    int fgrid;
    {
        int pre = 0; fa.blockPrefix[0] = 0;
        for (int t = 0; t < 7; t++) {
            fa.ns[t] = FEED_NS[t];
            fa.nodepre[t] = NODEPRE[t];
            fa.nrows[t] = NT[t];
            fa.invnd[t] = INVND[t];
            for (int j = 0; j < 6; j++) fa.a1off[t][j] = CNTOFF[FEED_E[t][j]];
            pre += (NT[t] + 63) / 64;
            fa.blockPrefix[t + 1] = pre;
        }
        fgrid = pre;
    }
    for (int l = 0; l < 3; l++) {
        agg_k<<<(TOTC + 15) / 16, 256, 0, stream>>>(cnt, cursor, invdeg, col, h_bf, slotb);
        for (int t = 0; t < 7; t++) {
            for (int j = 0; j < 6; j++) {
                int e = FEED_E[t][j];
                fa.W1[t][j]   = w_bf + (size_t)(7  + l * 14 + e) * 16384;
                fa.W2[t][j]   = w_bf + (size_t)(49 + l * 14 + e) * 16384;
                fa.bias[t][j] = bl + ((size_t)l * 14 + e) * HID;
            }
        }
        fusedln_k<<<fgrid, 256, 0, stream>>>(fa, h_bf, slotb, ln_g, ln_b, l);
    }

    // heads: l2norm(h @ W^T + b) -> fp32 out (overwrites the col scratch in d_out)
    {
        GemmArgs ga;
        ga.blockPrefix[0] = 0;
        ga.A1[0] = h_bf;
        ga.W1[0] = w_bf + (size_t)91 * 16384;
        ga.bias[0] = bu;                        ga.out[0] = out;
        ga.rows[0] = 100000;
        ga.blockPrefix[1] = (100000 + 63) / 64;
        ga.A1[1] = h_bf + (size_t)100000 * HID;
        ga.W1[1] = w_bf + (size_t)92 * 16384;
        ga.bias[1] = bv;                        ga.out[1] = out + (size_t)100000 * HID;
        ga.rows[1] = 40000;
        int tot = ga.blockPrefix[1] + (40000 + 63) / 64;
        for (int s = 2; s < 14; s++) { ga.blockPrefix[s + 1] = tot; ga.rows[s] = 0; }
        ga.blockPrefix[2] = tot;
        gemm_k<3><<<tot, 256, 0, stream>>>(ga);
    }
}